// Round 2
// baseline (739.815 us; speedup 1.0000x reference)
//
#include <hip/hip_runtime.h>

#define N_NODES 25600
#define F_IN 400
#define NE 512000
#define NB 64
#define NPG 400
#define EPG 8000
#define BN_EPS 1e-5f

#define S_ROWS 448
#define S_COLS 448
#define S_COLS2 (S_COLS / 2)
#define SB_RPB 112
#define K0PAD 448

#define NBLK 448            // persistent blocks; capacity >= 2/CU * 256 = 512 > 448 -> co-resident

// workspace offsets (256-aligned)
#define TT_OFF    0u
#define Z_OFF     6555648u
#define SB_OFF    13109248u
#define PSTAT_OFF 19531776u
#define WT0_OFF   19589120u
#define WTA1_OFF  19703808u
#define WTA2_OFF  19736576u
#define WTB0_OFF  19769344u
#define WTB1_OFF  19802112u
#define WTB2_OFF  19834880u
#define BAR_OFF   19867648u

typedef __attribute__((ext_vector_type(8))) short short8;
typedef __attribute__((ext_vector_type(4))) float floatx4;
typedef unsigned short us;

__device__ __forceinline__ unsigned short f2bf(float f) {
    unsigned int u = __float_as_uint(f);
    u += 0x7FFF + ((u >> 16) & 1);   // RNE
    return (unsigned short)(u >> 16);
}
__device__ __forceinline__ float bf2f(unsigned short s) {
    return __uint_as_float((unsigned int)s << 16);
}
__device__ __forceinline__ short u8bf(unsigned v) {
    return (short)(__float_as_uint((float)v) >> 16);
}

// ---- device-scope grid barrier (generation-based; bar[0]=count, bar[16]=gen, separate lines) ----
__device__ __forceinline__ void gsync(unsigned* bar) {
    __syncthreads();
    if (threadIdx.x == 0) {
        unsigned gen = __hip_atomic_load(bar + 16, __ATOMIC_ACQUIRE, __HIP_MEMORY_SCOPE_AGENT);
        __threadfence();   // release: make this block's writes agent-visible
        if (__hip_atomic_fetch_add(bar, 1u, __ATOMIC_ACQ_REL, __HIP_MEMORY_SCOPE_AGENT) == NBLK - 1u) {
            __hip_atomic_store(bar, 0u, __ATOMIC_RELAXED, __HIP_MEMORY_SCOPE_AGENT);
            __hip_atomic_fetch_add(bar + 16, 1u, __ATOMIC_RELEASE, __HIP_MEMORY_SCOPE_AGENT);
        } else {
            while (__hip_atomic_load(bar + 16, __ATOMIC_RELAXED, __HIP_MEMORY_SCOPE_AGENT) == gen)
                __builtin_amdgcn_s_sleep(8);
        }
        __threadfence();   // acquire: invalidate stale cached lines before next phase reads
    }
    __syncthreads();
}

// ---------------- P0: adjacency build (bid<256) + weight transposes + zero stats (bid>=256) ----------------

__device__ __forceinline__ void phase_prep(unsigned char* smem, int bid, int tid,
        const int* __restrict__ src, const int* __restrict__ dst, unsigned char* Sb,
        const float* __restrict__ wa0, const float* __restrict__ wa1, const float* __restrict__ wa2,
        const float* __restrict__ wb0, const float* __restrict__ wb1, const float* __restrict__ wb2,
        us* wt0, us* wta1, us* wta2, us* wtb0, us* wtb1, us* wtb2,
        float* pstat, us* tT) {
    if (bid < 256) {
        int* cnt32 = (int*)smem;     // 44.8 KB
        int g = bid >> 2, part = bid & 3;
        int r0 = part * SB_RPB;
        for (int i = tid; i < SB_RPB * NPG / 4; i += 256) cnt32[i] = 0;
        __syncthreads();
        int ebase = g * EPG, nbase = g * NPG;
        for (int e = tid; e < EPG; e += 256) {
            int d = dst[ebase + e] - nbase;
            int dr = d - r0;
            if ((unsigned)dr < (unsigned)SB_RPB) {
                int s = src[ebase + e] - nbase;
                int idx = dr * NPG + s;
                atomicAdd(&cnt32[idx >> 2], (int)(1u << ((idx & 3) * 8)));
            }
        }
        __syncthreads();
        const unsigned char* cb = (const unsigned char*)cnt32;
        for (int i = tid; i < SB_RPB * (S_COLS / 8); i += 256) {
            int rr = i / (S_COLS / 8), c8 = (i % (S_COLS / 8)) * 8;
            int R = r0 + rr;
            unsigned pk = 0;
#pragma unroll
            for (int j = 0; j < 8; ++j) {
                int c = c8 + j;
                unsigned v = 0;
                if (R < NPG && c < NPG) v = (unsigned)cb[rr * NPG + c] + (c == R ? 1u : 0u);
                pk |= (v & 15u) << (4 * j);
            }
            *(unsigned*)&Sb[((size_t)g * S_ROWS + R) * S_COLS2 + (c8 >> 1)] = pk;
        }
    } else {
        int base0 = (bid - 256) * 256 + tid;            // 0..49151 over 192 blocks
        if (base0 < 3 * 2048 + 8192) pstat[base0] = 0.f;
        if (base0 < 512) tT[(size_t)128 * N_NODES + base0] = 0;   // zero tT tail slack
#pragma unroll 1
        for (int pass = 0; pass < 3; ++pass) {
            int idx = base0 + pass * 49152;
            if (idx < 128 * K0PAD) {
                int n = idx / K0PAD, k = idx - n * K0PAD;
                wt0[idx] = (k < 400) ? f2bf(wa0[(size_t)k * 128 + n]) : (unsigned short)0;
            } else if (idx < 128 * K0PAD + 5 * 16384) {
                int r2 = idx - 128 * K0PAD;
                int seg = r2 >> 14, r = r2 & 16383;
                int n = r >> 7, k = r & 127;
                const float* s5[5] = {wb0, wa1, wb1, wa2, wb2};
                us* d5[5] = {wtb0, wta1, wtb1, wta2, wtb2};
                d5[seg][r] = f2bf(s5[seg][(size_t)k * 128 + n]);
            }
        }
    }
}

// ---------------- P1: tT = ([x | ge | he] @ W0a)^T, bf16, M=64 tiles, BK=64 ----------------

__device__ __forceinline__ void phase_embed(unsigned char* smem, int bid, int tid,
        const float* __restrict__ A, const us* Wt, const float* __restrict__ Wfull,
        const int* __restrict__ gid, const float* __restrict__ ge, const float* __restrict__ he,
        us* CtT) {
    if (bid >= 400) return;
    us (*As)[72] = (us(*)[72])smem;
    us (*Bs)[72] = (us(*)[72])(smem + 9216);
    float (*Wex)[128] = (float(*)[128])(smem + 27648);
    int m0 = bid * 64;
    int wave = tid >> 6, lane = tid & 63;
    int wcol = wave * 32;
    int fm = lane & 15, quad = lane >> 4;

    for (int i = tid; i < 512; i += 256)
        Wex[i >> 7][i & 127] = Wfull[(size_t)(400 + (i >> 7)) * 128 + (i & 127)];

    floatx4 acc[4][2];
#pragma unroll
    for (int rt = 0; rt < 4; ++rt)
#pragma unroll
        for (int ct = 0; ct < 2; ++ct) acc[rt][ct] = (floatx4){0.f, 0.f, 0.f, 0.f};

    const int rA = tid >> 2, kcA = (tid & 3) * 16;
    const int nB = tid >> 1, kcB = (tid & 1) * 32;
    float4 aP0, aP1, aP2, aP3;
    short8 bP0, bP1, bP2, bP3;

    auto loadK = [&](int ks) {
        int k0 = ks * 64;
        int kg = k0 + kcA;
        const float* ar = A + (size_t)(m0 + rA) * F_IN;
        if (kg + 15 < 400) {
            aP0 = *(const float4*)(ar + kg);
            aP1 = *(const float4*)(ar + kg + 4);
            aP2 = *(const float4*)(ar + kg + 8);
            aP3 = *(const float4*)(ar + kg + 12);
        } else {
            float v[16];
#pragma unroll
            for (int j = 0; j < 16; ++j) v[j] = (kg + j < 400) ? ar[kg + j] : 0.f;
            aP0 = (float4){v[0], v[1], v[2], v[3]};
            aP1 = (float4){v[4], v[5], v[6], v[7]};
            aP2 = (float4){v[8], v[9], v[10], v[11]};
            aP3 = (float4){v[12], v[13], v[14], v[15]};
        }
        const us* wr = Wt + (size_t)nB * K0PAD + k0 + kcB;
        bP0 = *(const short8*)wr;
        bP1 = *(const short8*)(wr + 8);
        bP2 = *(const short8*)(wr + 16);
        bP3 = *(const short8*)(wr + 24);
    };

    loadK(0);
    for (int ks = 0; ks < 7; ++ks) {
        {
            short8 s0, s1;
            s0[0] = (short)f2bf(aP0.x); s0[1] = (short)f2bf(aP0.y);
            s0[2] = (short)f2bf(aP0.z); s0[3] = (short)f2bf(aP0.w);
            s0[4] = (short)f2bf(aP1.x); s0[5] = (short)f2bf(aP1.y);
            s0[6] = (short)f2bf(aP1.z); s0[7] = (short)f2bf(aP1.w);
            s1[0] = (short)f2bf(aP2.x); s1[1] = (short)f2bf(aP2.y);
            s1[2] = (short)f2bf(aP2.z); s1[3] = (short)f2bf(aP2.w);
            s1[4] = (short)f2bf(aP3.x); s1[5] = (short)f2bf(aP3.y);
            s1[6] = (short)f2bf(aP3.z); s1[7] = (short)f2bf(aP3.w);
            *(short8*)&As[rA][kcA] = s0;
            *(short8*)&As[rA][kcA + 8] = s1;
            *(short8*)&Bs[nB][kcB] = bP0;
            *(short8*)&Bs[nB][kcB + 8] = bP1;
            *(short8*)&Bs[nB][kcB + 16] = bP2;
            *(short8*)&Bs[nB][kcB + 24] = bP3;
        }
        __syncthreads();
        if (ks + 1 < 7) loadK(ks + 1);
#pragma unroll
        for (int k0l = 0; k0l < 64; k0l += 32) {
            short8 af[4], bf[2];
#pragma unroll
            for (int rt = 0; rt < 4; ++rt)
                af[rt] = *(const short8*)&As[rt * 16 + fm][k0l + quad * 8];
#pragma unroll
            for (int ct = 0; ct < 2; ++ct)
                bf[ct] = *(const short8*)&Bs[wcol + ct * 16 + fm][k0l + quad * 8];
#pragma unroll
            for (int rt = 0; rt < 4; ++rt)
#pragma unroll
                for (int ct = 0; ct < 2; ++ct)
                    acc[rt][ct] = __builtin_amdgcn_mfma_f32_16x16x32_bf16(
                        af[rt], bf[ct], acc[rt][ct], 0, 0, 0);
        }
        __syncthreads();
    }

#pragma unroll
    for (int rt = 0; rt < 4; ++rt) {
#pragma unroll
        for (int ct = 0; ct < 2; ++ct) {
            int col = wcol + ct * 16 + fm;
            int row0 = m0 + rt * 16 + quad * 4;
            ushort4 o;
#pragma unroll
            for (int r = 0; r < 4; ++r) {
                int row = row0 + r;
                int gv = gid[row];
                float v = acc[rt][ct][r]
                        + ge[gv * 2] * Wex[0][col] + ge[gv * 2 + 1] * Wex[1][col]
                        + he[(row & 1) * 2] * Wex[2][col] + he[(row & 1) * 2 + 1] * Wex[3][col];
                ((unsigned short*)&o)[r] = f2bf(v);
            }
            *(ushort4*)&CtT[(size_t)col * N_NODES + row0] = o;
        }
    }
}

// ---------------- agg: z = (S+I)@t + bias (bf16), atomic BN partials; all 448 blocks ----------------

__device__ __forceinline__ void phase_agg(unsigned char* smem, int bid, int tid,
        const unsigned char* Sb, const us* tT, const float* __restrict__ bias,
        us* z, float* psumG, float* psqG) {
    us (*As)[72] = (us(*)[72])smem;
    us (*Bs)[72] = (us(*)[72])(smem + 9216);
    float (*sw)[2][16] = (float(*)[2][16])(smem + 27648);
    float (*qw)[2][16] = (float(*)[2][16])(smem + 28160);
    int g = bid & 63;
    int tile = bid >> 6;
    int m0l = tile * 64;
    int node0 = g * NPG;
    int wave = tid >> 6, lane = tid & 63;
    int wcol = wave * 32;
    int fm = lane & 15, quad = lane >> 4;

    floatx4 acc[4][2];
#pragma unroll
    for (int rt = 0; rt < 4; ++rt)
#pragma unroll
        for (int ct = 0; ct < 2; ++ct) acc[rt][ct] = (floatx4){0.f, 0.f, 0.f, 0.f};

    const int rA = tid >> 2, kcA = (tid & 3) * 16;
    const int nB = tid >> 1, kcB = (tid & 1) * 32;
    unsigned long long aP;
    short8 bP0, bP1, bP2, bP3;

    auto loadK = [&](int ks) {
        int k0 = ks * 64;
        aP = *(const unsigned long long*)(Sb + ((size_t)g * S_ROWS + m0l + rA) * S_COLS2 + ((k0 + kcA) >> 1));
        const us* p = tT + (size_t)nB * N_NODES + node0 + k0 + kcB;
        bP0 = *(const short8*)p;
        bP1 = *(const short8*)(p + 8);
        bP2 = *(const short8*)(p + 16);
        bP3 = *(const short8*)(p + 24);
    };

    loadK(0);
    for (int ks = 0; ks < S_COLS / 64; ++ks) {
        {
            short8 s0, s1;
#pragma unroll
            for (int j = 0; j < 8; ++j) s0[j] = u8bf((unsigned)(aP >> (4 * j)) & 15u);
#pragma unroll
            for (int j = 0; j < 8; ++j) s1[j] = u8bf((unsigned)(aP >> (32 + 4 * j)) & 15u);
            *(short8*)&As[rA][kcA] = s0;
            *(short8*)&As[rA][kcA + 8] = s1;
            *(short8*)&Bs[nB][kcB] = bP0;
            *(short8*)&Bs[nB][kcB + 8] = bP1;
            *(short8*)&Bs[nB][kcB + 16] = bP2;
            *(short8*)&Bs[nB][kcB + 24] = bP3;
        }
        __syncthreads();
        if (ks + 1 < S_COLS / 64) loadK(ks + 1);
#pragma unroll
        for (int k0l = 0; k0l < 64; k0l += 32) {
            short8 af[4], bf[2];
#pragma unroll
            for (int rt = 0; rt < 4; ++rt)
                af[rt] = *(const short8*)&As[rt * 16 + fm][k0l + quad * 8];
#pragma unroll
            for (int ct = 0; ct < 2; ++ct)
                bf[ct] = *(const short8*)&Bs[wcol + ct * 16 + fm][k0l + quad * 8];
#pragma unroll
            for (int rt = 0; rt < 4; ++rt)
#pragma unroll
                for (int ct = 0; ct < 2; ++ct)
                    acc[rt][ct] = __builtin_amdgcn_mfma_f32_16x16x32_bf16(
                        af[rt], bf[ct], acc[rt][ct], 0, 0, 0);
        }
        __syncthreads();
    }

    {
        float scol[2] = {0.f, 0.f}, qcol[2] = {0.f, 0.f};
#pragma unroll
        for (int rt = 0; rt < 4; ++rt) {
#pragma unroll
            for (int ct = 0; ct < 2; ++ct) {
                int col = wcol + ct * 16 + fm;
                float bv = bias[col];
                int rbase = m0l + rt * 16 + quad * 4;
#pragma unroll
                for (int r = 0; r < 4; ++r) {
                    int rloc = rbase + r;
                    if (rloc < NPG) {
                        float v = acc[rt][ct][r] + bv;
                        z[(size_t)(node0 + rloc) * 128 + col] = f2bf(v);
                        scol[ct] += v;
                        qcol[ct] += v * v;
                    }
                }
            }
        }
#pragma unroll
        for (int ct = 0; ct < 2; ++ct) {
            scol[ct] += __shfl_xor(scol[ct], 16);
            scol[ct] += __shfl_xor(scol[ct], 32);
            qcol[ct] += __shfl_xor(qcol[ct], 16);
            qcol[ct] += __shfl_xor(qcol[ct], 32);
        }
        if (lane < 16) {
#pragma unroll
            for (int ct = 0; ct < 2; ++ct) { sw[wave][ct][lane] = scol[ct]; qw[wave][ct][lane] = qcol[ct]; }
        }
    }
    __syncthreads();
    if (tid < 128) {
        int c = tid;
        int wv = c >> 5, ct = (c >> 4) & 1, f = c & 15;
        int bucket = bid & 7;
        atomicAdd(&psumG[bucket * 128 + c], sw[wv][ct][f]);
        atomicAdd(&psqG[bucket * 128 + c], qw[wv][ct][f]);
    }
}

// ---------------- post: BN + h = relu(relu(affine(z))@wb+bb) [+ t'=h@wa_next | pool] ----------------

#define MODE_FUSED 0
#define MODE_FINAL 1

template <int MODE>
__device__ __forceinline__ void phase_post(unsigned char* smem, int bid, int tid,
        const us* z, const float* psumG, const float* psqG,
        const float* __restrict__ gamma, const float* __restrict__ beta,
        const us* wtb, const float* __restrict__ bb,
        const us* wta_next, us* CtT, float* pooled) {
    if (bid >= 400) return;
    us (*hs)[136] = (us(*)[136])smem;          // phase-1 A tile (cols 0..71), then h
    us (*Bs)[72]  = (us(*)[72])(smem + 17408);
    float* coefs  = (float*)(smem + 35840);
    int m0 = bid * 64;
    int wave = tid >> 6, lane = tid & 63;
    int wcol = wave * 32;
    int fm = lane & 15, quad = lane >> 4;

    if (tid < 128) {
        float S = 0.f, Q = 0.f;
#pragma unroll
        for (int b = 0; b < 8; ++b) { S += psumG[b * 128 + tid]; Q += psqG[b * 128 + tid]; }
        float invn = 1.0f / (float)N_NODES;
        float mu = S * invn;
        float var = Q * invn - mu * mu;
        float a = gamma[tid] * rsqrtf(var + BN_EPS);
        coefs[tid] = a;
        coefs[128 + tid] = beta[tid] - a * mu;
    }
    __syncthreads();

    floatx4 acc[4][2];
#pragma unroll
    for (int rt = 0; rt < 4; ++rt)
#pragma unroll
        for (int ct = 0; ct < 2; ++ct) acc[rt][ct] = (floatx4){0.f, 0.f, 0.f, 0.f};

    const int rA = tid >> 2, kcA = (tid & 3) * 16;
    const int nB = tid >> 1, kcB = (tid & 1) * 32;
    short8 aPa, aPb;
    short8 bP0, bP1, bP2, bP3;

    auto loadK1 = [&](int ks) {
        int k0 = ks * 64;
        const us* zr = &z[(size_t)(m0 + rA) * 128 + k0 + kcA];
        aPa = *(const short8*)zr;
        aPb = *(const short8*)(zr + 8);
        const us* wr = wtb + (size_t)nB * 128 + k0 + kcB;
        bP0 = *(const short8*)wr;
        bP1 = *(const short8*)(wr + 8);
        bP2 = *(const short8*)(wr + 16);
        bP3 = *(const short8*)(wr + 24);
    };

    loadK1(0);
    for (int ks = 0; ks < 2; ++ks) {
        {
            int kg = ks * 64 + kcA;
            short8 s0, s1;
#pragma unroll
            for (int j = 0; j < 8; ++j) {
                float v = fmaxf(coefs[kg + j] * bf2f((unsigned short)aPa[j]) + coefs[128 + kg + j], 0.f);
                s0[j] = (short)f2bf(v);
            }
#pragma unroll
            for (int j = 0; j < 8; ++j) {
                float v = fmaxf(coefs[kg + 8 + j] * bf2f((unsigned short)aPb[j]) + coefs[128 + kg + 8 + j], 0.f);
                s1[j] = (short)f2bf(v);
            }
            *(short8*)&hs[rA][kcA] = s0;
            *(short8*)&hs[rA][kcA + 8] = s1;
            *(short8*)&Bs[nB][kcB] = bP0;
            *(short8*)&Bs[nB][kcB + 8] = bP1;
            *(short8*)&Bs[nB][kcB + 16] = bP2;
            *(short8*)&Bs[nB][kcB + 24] = bP3;
        }
        __syncthreads();
        if (ks + 1 < 2) loadK1(ks + 1);
#pragma unroll
        for (int k0l = 0; k0l < 64; k0l += 32) {
            short8 af[4], bf[2];
#pragma unroll
            for (int rt = 0; rt < 4; ++rt)
                af[rt] = *(const short8*)&hs[rt * 16 + fm][k0l + quad * 8];
#pragma unroll
            for (int ct = 0; ct < 2; ++ct)
                bf[ct] = *(const short8*)&Bs[wcol + ct * 16 + fm][k0l + quad * 8];
#pragma unroll
            for (int rt = 0; rt < 4; ++rt)
#pragma unroll
                for (int ct = 0; ct < 2; ++ct)
                    acc[rt][ct] = __builtin_amdgcn_mfma_f32_16x16x32_bf16(
                        af[rt], bf[ct], acc[rt][ct], 0, 0, 0);
        }
        __syncthreads();
    }

    if (MODE == MODE_FINAL) {
        float rsum[4][2];
#pragma unroll
        for (int rt = 0; rt < 4; ++rt)
#pragma unroll
            for (int ct = 0; ct < 2; ++ct) {
                int col = wcol + ct * 16 + fm;
                float bv = bb[col];
                float s = 0.f;
#pragma unroll
                for (int r = 0; r < 4; ++r) s += fmaxf(acc[rt][ct][r] + bv, 0.f);
                rsum[rt][ct] = s;
            }
        bool uniform = (m0 / NPG) == ((m0 + 63) / NPG);
        if (uniform) {
            int gph = m0 / NPG;
#pragma unroll
            for (int ct = 0; ct < 2; ++ct) {
                float cs = rsum[0][ct] + rsum[1][ct] + rsum[2][ct] + rsum[3][ct];
                cs += __shfl_xor(cs, 16);
                cs += __shfl_xor(cs, 32);
                if (lane < 16) atomicAdd(&pooled[gph * 128 + wcol + ct * 16 + fm], cs);
            }
        } else {
#pragma unroll
            for (int rt = 0; rt < 4; ++rt)
#pragma unroll
                for (int ct = 0; ct < 2; ++ct) {
                    int gph = (m0 + rt * 16 + quad * 4) / NPG;
                    atomicAdd(&pooled[gph * 128 + wcol + ct * 16 + fm], rsum[rt][ct]);
                }
        }
        return;
    }

#pragma unroll
    for (int rt = 0; rt < 4; ++rt)
#pragma unroll
        for (int ct = 0; ct < 2; ++ct) {
            int col = wcol + ct * 16 + fm;
            float bv = bb[col];
            int rbase = rt * 16 + quad * 4;
#pragma unroll
            for (int r = 0; r < 4; ++r)
                hs[rbase + r][col] = f2bf(fmaxf(acc[rt][ct][r] + bv, 0.f));
        }
    __syncthreads();

#pragma unroll
    for (int rt = 0; rt < 4; ++rt)
#pragma unroll
        for (int ct = 0; ct < 2; ++ct) acc[rt][ct] = (floatx4){0.f, 0.f, 0.f, 0.f};

    const int kcB2 = (tid & 1) * 16;
    for (int ks = 0; ks < 4; ++ks) {
        int k0 = ks * 32;
        {
            const us* wr = wta_next + (size_t)nB * 128 + k0 + kcB2;
            *(short8*)&Bs[nB][kcB2] = *(const short8*)wr;
            *(short8*)&Bs[nB][kcB2 + 8] = *(const short8*)(wr + 8);
        }
        __syncthreads();
        {
            short8 af[4], bf[2];
#pragma unroll
            for (int rt = 0; rt < 4; ++rt)
                af[rt] = *(const short8*)&hs[rt * 16 + fm][k0 + quad * 8];
#pragma unroll
            for (int ct = 0; ct < 2; ++ct)
                bf[ct] = *(const short8*)&Bs[wcol + ct * 16 + fm][quad * 8];
#pragma unroll
            for (int rt = 0; rt < 4; ++rt)
#pragma unroll
                for (int ct = 0; ct < 2; ++ct)
                    acc[rt][ct] = __builtin_amdgcn_mfma_f32_16x16x32_bf16(
                        af[rt], bf[ct], acc[rt][ct], 0, 0, 0);
        }
        __syncthreads();
    }

#pragma unroll
    for (int rt = 0; rt < 4; ++rt)
#pragma unroll
        for (int ct = 0; ct < 2; ++ct) {
            int col = wcol + ct * 16 + fm;
            int row0 = m0 + rt * 16 + quad * 4;
            ushort4 o;
#pragma unroll
            for (int r = 0; r < 4; ++r) ((unsigned short*)&o)[r] = f2bf(acc[rt][ct][r]);
            *(ushort4*)&CtT[(size_t)col * N_NODES + row0] = o;
        }
}

// ---------------- the one persistent kernel ----------------

__global__ __launch_bounds__(256, 2) void fused_all(
        const float* __restrict__ x, const int* __restrict__ esrc, const int* __restrict__ edst,
        const int* __restrict__ gid, const float* __restrict__ ge, const float* __restrict__ he,
        const float* __restrict__ wa0, const float* __restrict__ ba0, const float* __restrict__ gg0,
        const float* __restrict__ be0, const float* __restrict__ wb0, const float* __restrict__ bbias0,
        const float* __restrict__ wa1, const float* __restrict__ ba1, const float* __restrict__ gg1,
        const float* __restrict__ be1, const float* __restrict__ wb1, const float* __restrict__ bbias1,
        const float* __restrict__ wa2, const float* __restrict__ ba2, const float* __restrict__ gg2,
        const float* __restrict__ be2, const float* __restrict__ wb2, const float* __restrict__ bbias2,
        const float* __restrict__ wfa, const float* __restrict__ bfa,
        const float* __restrict__ wfb, const float* __restrict__ bfb,
        float* __restrict__ out, unsigned char* ws) {
    __shared__ __align__(16) unsigned char smem[44800];
    us* tT = (us*)(ws + TT_OFF);
    us* z  = (us*)(ws + Z_OFF);
    unsigned char* Sb = ws + SB_OFF;
    float* pstat = (float*)(ws + PSTAT_OFF);
    us* wt0  = (us*)(ws + WT0_OFF);
    us* wta1 = (us*)(ws + WTA1_OFF);
    us* wta2 = (us*)(ws + WTA2_OFF);
    us* wtb0 = (us*)(ws + WTB0_OFF);
    us* wtb1 = (us*)(ws + WTB1_OFF);
    us* wtb2 = (us*)(ws + WTB2_OFF);
    unsigned* bar = (unsigned*)(ws + BAR_OFF);
    float* pooled = pstat + 6144;
    int bid = blockIdx.x, tid = threadIdx.x;

    phase_prep(smem, bid, tid, esrc, edst, Sb, wa0, wa1, wa2, wb0, wb1, wb2,
               wt0, wta1, wta2, wtb0, wtb1, wtb2, pstat, tT);
    gsync(bar);
    phase_embed(smem, bid, tid, x, wt0, wa0, gid, ge, he, tT);
    gsync(bar);
    phase_agg(smem, bid, tid, Sb, tT, ba0, z, pstat + 0, pstat + 1024);
    gsync(bar);
    phase_post<MODE_FUSED>(smem, bid, tid, z, pstat + 0, pstat + 1024, gg0, be0,
                           wtb0, bbias0, wta1, tT, nullptr);
    gsync(bar);
    phase_agg(smem, bid, tid, Sb, tT, ba1, z, pstat + 2048, pstat + 3072);
    gsync(bar);
    phase_post<MODE_FUSED>(smem, bid, tid, z, pstat + 2048, pstat + 3072, gg1, be1,
                           wtb1, bbias1, wta2, tT, nullptr);
    gsync(bar);
    phase_agg(smem, bid, tid, Sb, tT, ba2, z, pstat + 4096, pstat + 5120);
    gsync(bar);
    phase_post<MODE_FINAL>(smem, bid, tid, z, pstat + 4096, pstat + 5120, gg2, be2,
                           wtb2, bbias2, nullptr, nullptr, pooled);
    gsync(bar);

    // head: relu(pooled@wfa+bfa) @ wfb + bfb
    if (bid < 64) {
        float* pl = (float*)smem;
        float* o0 = (float*)smem + 128;
        float* o1 = (float*)smem + 256;
        int f = tid;
        if (f < 128) pl[f] = pooled[bid * 128 + f];
        __syncthreads();
        if (f < 128) {
            float a = bfa[f];
            for (int k = 0; k < 128; ++k) a += pl[k] * wfa[k * 128 + f];
            float p2 = fmaxf(a, 0.f);
            o0[f] = p2 * wfb[f * 2 + 0];
            o1[f] = p2 * wfb[f * 2 + 1];
        }
        __syncthreads();
        if (f == 0) {
            float a0 = bfb[0], a1 = bfb[1];
#pragma unroll
            for (int k = 0; k < 128; ++k) { a0 += o0[k]; a1 += o1[k]; }
            out[bid * 2 + 0] = a0;
            out[bid * 2 + 1] = a1;
        }
    }
}

// ---------------- launch ----------------

extern "C" void kernel_launch(void* const* d_in, const int* in_sizes, int n_in,
                              void* d_out, int out_size, void* d_ws, size_t ws_size,
                              hipStream_t stream) {
    const float* x   = (const float*)d_in[0];
    const int* ei    = (const int*)d_in[1];
    const int* gid   = (const int*)d_in[3];
    const float* ge  = (const float*)d_in[4];
    const float* he  = (const float*)d_in[5];
    float* out = (float*)d_out;
    unsigned char* ws = (unsigned char*)d_ws;
    (void)ws_size; (void)in_sizes; (void)n_in; (void)out_size;

    hipMemsetAsync(ws + BAR_OFF, 0, 256, stream);   // barrier state (count+gen)

    fused_all<<<NBLK, 256, 0, stream>>>(
        x, ei, ei + NE, gid, ge, he,
        (const float*)d_in[6],  (const float*)d_in[7],  (const float*)d_in[8],
        (const float*)d_in[9],  (const float*)d_in[10], (const float*)d_in[11],
        (const float*)d_in[12], (const float*)d_in[13], (const float*)d_in[14],
        (const float*)d_in[15], (const float*)d_in[16], (const float*)d_in[17],
        (const float*)d_in[18], (const float*)d_in[19], (const float*)d_in[20],
        (const float*)d_in[21], (const float*)d_in[22], (const float*)d_in[23],
        (const float*)d_in[24], (const float*)d_in[25],
        (const float*)d_in[26], (const float*)d_in[27],
        out, ws);
}

// Round 3
// 347.612 us; speedup vs baseline: 2.1283x; 2.1283x over previous
//
#include <hip/hip_runtime.h>

#define N_NODES 25600
#define F_IN 400
#define NE 512000
#define NB 64
#define NPG 400
#define EPG 8000
#define BN_EPS 1e-5f

#define S_ROWS 448
#define S_COLS 448
#define S_COLS2 (S_COLS / 2)
#define SB_RPB 112
#define K0PAD 448

typedef __attribute__((ext_vector_type(8))) short short8;
typedef __attribute__((ext_vector_type(4))) float floatx4;
typedef unsigned short us;
typedef unsigned long long u64;

__device__ __forceinline__ unsigned short f2bf(float f) {
    unsigned int u = __float_as_uint(f);
    u += 0x7FFF + ((u >> 16) & 1);   // RNE
    return (unsigned short)(u >> 16);
}
__device__ __forceinline__ float bf2f(unsigned short s) {
    return __uint_as_float((unsigned int)s << 16);
}
// exact for integers 0..255
__device__ __forceinline__ short u8bf(unsigned v) {
    return (short)(__float_as_uint((float)v) >> 16);
}

// ---------------- prep: u4 adjacency + weight transposes + zero stats/slack ----------------

__global__ __launch_bounds__(256) void prep(const int* __restrict__ src,
                                            const int* __restrict__ dst,
                                            unsigned char* __restrict__ Sb,
                                            const float* __restrict__ wa0, const float* __restrict__ wa1,
                                            const float* __restrict__ wa2, const float* __restrict__ wb0,
                                            const float* __restrict__ wb1, const float* __restrict__ wb2,
                                            us* __restrict__ t0, us* __restrict__ t1,
                                            us* __restrict__ t2, us* __restrict__ t3,
                                            us* __restrict__ t4, us* __restrict__ t5,
                                            float* __restrict__ pstat, us* __restrict__ tTz) {
    __shared__ int cnt32[SB_RPB * NPG / 4];   // 44.8 KB
    int tid = threadIdx.x;
    if (blockIdx.x < 256) {
        int b = blockIdx.x;
        int g = b >> 2, part = b & 3;
        int r0 = part * SB_RPB;
        for (int i = tid; i < SB_RPB * NPG / 4; i += 256) cnt32[i] = 0;
        __syncthreads();
        int ebase = g * EPG, nbase = g * NPG;
        for (int e = tid; e < EPG; e += 256) {
            int d = dst[ebase + e] - nbase;
            int dr = d - r0;
            if ((unsigned)dr < (unsigned)SB_RPB) {
                int s = src[ebase + e] - nbase;
                int idx = dr * NPG + s;
                atomicAdd(&cnt32[idx >> 2], (int)(1u << ((idx & 3) * 8)));
            }
        }
        __syncthreads();
        const unsigned char* cb = (const unsigned char*)cnt32;
        for (int i = tid; i < SB_RPB * (S_COLS / 8); i += 256) {
            int rr = i / (S_COLS / 8), c8 = (i % (S_COLS / 8)) * 8;
            int R = r0 + rr;
            unsigned pk = 0;
#pragma unroll
            for (int j = 0; j < 8; ++j) {
                int c = c8 + j;
                unsigned v = 0;
                if (R < NPG && c < NPG) v = (unsigned)cb[rr * NPG + c] + (c == R ? 1u : 0u);
                pk |= (v & 15u) << (4 * j);
            }
            *(unsigned*)&Sb[((size_t)g * S_ROWS + R) * S_COLS2 + (c8 >> 1)] = pk;
        }
        return;
    }
    int idx = (blockIdx.x - 256) * 256 + tid;
    if (idx < 3 * 2048 + 8192) pstat[idx] = 0.f;
    if (idx < 512) tTz[(size_t)128 * N_NODES + idx] = 0;   // zero tT tail slack
    if (idx < 128 * K0PAD) {
        int n = idx / K0PAD, k = idx - n * K0PAD;
        t0[idx] = (k < 400) ? f2bf(wa0[(size_t)k * 128 + n]) : (unsigned short)0;
        return;
    }
    idx -= 128 * K0PAD;
    if (idx >= 5 * 128 * 128) return;
    int seg = idx >> 14;
    int r = idx & 16383;
    int n = r >> 7, k = r & 127;
    const float* srcs[5] = {wb0, wa1, wb1, wa2, wb2};
    us* dsts[5] = {t3, t1, t4, t2, t5};
    dsts[seg][r] = f2bf(srcs[seg][(size_t)k * 128 + n]);
}

// ---------------- embed: tT = ([x | ge | he] @ W0a)^T, bf16, full-chip (400 blocks) ----------------

__global__ __launch_bounds__(256) void gemm_embed64(const float* __restrict__ A,
                                                    const us* __restrict__ Wt,
                                                    const float* __restrict__ Wfull,
                                                    const int* __restrict__ gid,
                                                    const float* __restrict__ ge,
                                                    const float* __restrict__ he,
                                                    us* __restrict__ CtT) {
    __shared__ __align__(16) us As[64][72];
    __shared__ __align__(16) us Bs[128][72];
    __shared__ float Wex[4][128];
    int tid = threadIdx.x;
    int m0 = blockIdx.x * 64;
    int wave = tid >> 6, lane = tid & 63;
    int wcol = wave * 32;
    int fm = lane & 15, quad = lane >> 4;

    for (int i = tid; i < 512; i += 256)
        Wex[i >> 7][i & 127] = Wfull[(size_t)(400 + (i >> 7)) * 128 + (i & 127)];

    floatx4 acc[4][2];
#pragma unroll
    for (int rt = 0; rt < 4; ++rt)
#pragma unroll
        for (int ct = 0; ct < 2; ++ct) acc[rt][ct] = (floatx4){0.f, 0.f, 0.f, 0.f};

    const int rA = tid >> 2, kcA = (tid & 3) * 16;
    const int nB = tid >> 1, kcB = (tid & 1) * 32;
    float4 aP0, aP1, aP2, aP3;
    short8 bP0, bP1, bP2, bP3;

    auto loadK = [&](int ks) {
        int k0 = ks * 64;
        int kg = k0 + kcA;
        const float* ar = A + (size_t)(m0 + rA) * F_IN;
        if (kg + 15 < 400) {
            aP0 = *(const float4*)(ar + kg);
            aP1 = *(const float4*)(ar + kg + 4);
            aP2 = *(const float4*)(ar + kg + 8);
            aP3 = *(const float4*)(ar + kg + 12);
        } else {
            float v[16];
#pragma unroll
            for (int j = 0; j < 16; ++j) v[j] = (kg + j < 400) ? ar[kg + j] : 0.f;
            aP0 = (float4){v[0], v[1], v[2], v[3]};
            aP1 = (float4){v[4], v[5], v[6], v[7]};
            aP2 = (float4){v[8], v[9], v[10], v[11]};
            aP3 = (float4){v[12], v[13], v[14], v[15]};
        }
        const us* wr = Wt + (size_t)nB * K0PAD + k0 + kcB;
        bP0 = *(const short8*)wr;
        bP1 = *(const short8*)(wr + 8);
        bP2 = *(const short8*)(wr + 16);
        bP3 = *(const short8*)(wr + 24);
    };

    loadK(0);
    for (int ks = 0; ks < 7; ++ks) {
        {
            short8 s0, s1;
            s0[0] = (short)f2bf(aP0.x); s0[1] = (short)f2bf(aP0.y);
            s0[2] = (short)f2bf(aP0.z); s0[3] = (short)f2bf(aP0.w);
            s0[4] = (short)f2bf(aP1.x); s0[5] = (short)f2bf(aP1.y);
            s0[6] = (short)f2bf(aP1.z); s0[7] = (short)f2bf(aP1.w);
            s1[0] = (short)f2bf(aP2.x); s1[1] = (short)f2bf(aP2.y);
            s1[2] = (short)f2bf(aP2.z); s1[3] = (short)f2bf(aP2.w);
            s1[4] = (short)f2bf(aP3.x); s1[5] = (short)f2bf(aP3.y);
            s1[6] = (short)f2bf(aP3.z); s1[7] = (short)f2bf(aP3.w);
            *(short8*)&As[rA][kcA] = s0;
            *(short8*)&As[rA][kcA + 8] = s1;
            *(short8*)&Bs[nB][kcB] = bP0;
            *(short8*)&Bs[nB][kcB + 8] = bP1;
            *(short8*)&Bs[nB][kcB + 16] = bP2;
            *(short8*)&Bs[nB][kcB + 24] = bP3;
        }
        __syncthreads();
        if (ks + 1 < 7) loadK(ks + 1);
#pragma unroll
        for (int k0l = 0; k0l < 64; k0l += 32) {
            short8 af[4], bf[2];
#pragma unroll
            for (int rt = 0; rt < 4; ++rt)
                af[rt] = *(const short8*)&As[rt * 16 + fm][k0l + quad * 8];
#pragma unroll
            for (int ct = 0; ct < 2; ++ct)
                bf[ct] = *(const short8*)&Bs[wcol + ct * 16 + fm][k0l + quad * 8];
#pragma unroll
            for (int rt = 0; rt < 4; ++rt)
#pragma unroll
                for (int ct = 0; ct < 2; ++ct)
                    acc[rt][ct] = __builtin_amdgcn_mfma_f32_16x16x32_bf16(
                        af[rt], bf[ct], acc[rt][ct], 0, 0, 0);
        }
        __syncthreads();
    }

#pragma unroll
    for (int rt = 0; rt < 4; ++rt) {
#pragma unroll
        for (int ct = 0; ct < 2; ++ct) {
            int col = wcol + ct * 16 + fm;
            int row0 = m0 + rt * 16 + quad * 4;
            ushort4 o;
#pragma unroll
            for (int r = 0; r < 4; ++r) {
                int row = row0 + r;
                int gv = gid[row];
                float v = acc[rt][ct][r]
                        + ge[gv * 2] * Wex[0][col] + ge[gv * 2 + 1] * Wex[1][col]
                        + he[(row & 1) * 2] * Wex[2][col] + he[(row & 1) * 2 + 1] * Wex[3][col];
                ((unsigned short*)&o)[r] = f2bf(v);
            }
            *(ushort4*)&CtT[(size_t)col * N_NODES + row0] = o;
        }
    }
}

// ---------------- persistent per-graph kernel: 64 blocks x 1024 threads ----------------
// All heavy data (t, z) is block-private -> no cross-block coherence needed.
// Only cross-block traffic: BN partial sums via device-scope atomics (coherence point; no fences).

// LDS layout (static 59.4 KB): see offsets in each phase.

__device__ __forceinline__ void gbar(unsigned* bar, unsigned tgt) {
    __syncthreads();                     // drains each wave's vmcnt before arrival
    if (threadIdx.x == 0) {
        __hip_atomic_fetch_add(bar, 1u, __ATOMIC_RELAXED, __HIP_MEMORY_SCOPE_AGENT);
        while (__hip_atomic_load(bar, __ATOMIC_RELAXED, __HIP_MEMORY_SCOPE_AGENT) < tgt)
            __builtin_amdgcn_s_sleep(8);
        asm volatile("" ::: "memory");
    }
    __syncthreads();
}

__device__ __forceinline__ void p_agg(unsigned char* smem, int g, int tid,
        const unsigned char* __restrict__ Sb, const us* __restrict__ tT,
        const float* __restrict__ ba, us* __restrict__ zg,
        float* __restrict__ psum, float* __restrict__ psq, int bucket) {
    us (*As)[72] = (us(*)[72])smem;                              // 256x72x2 = 36864
    us (*Bs)[72] = (us(*)[72])(smem + 36864);                    // 128x72x2 = 18432
    float (*rs)[4][2][16] = (float(*)[4][2][16])(smem + 55296);  // 2048
    float (*rq)[4][2][16] = (float(*)[4][2][16])(smem + 57344);  // 2048
    int wave = tid >> 6, lane = tid & 63;
    int wrow = wave >> 2, wc4 = wave & 3;
    int wcol = wc4 * 32;
    int fm = lane & 15, quad = lane >> 4;
    int node0 = g * NPG;
    const int rA = tid >> 2, kcA = (tid & 3) * 16;   // 256 rows x 64 nibbles; 8 B/thread
    const int nB = tid >> 3, kcB = (tid & 7) * 8;    // 128 rows x 64 us; 16 B/thread
    float scol[2] = {0.f, 0.f}, qcol[2] = {0.f, 0.f};

    for (int R0 = 0; R0 < 400; R0 += 256) {
        floatx4 acc[4][2];
#pragma unroll
        for (int rt = 0; rt < 4; ++rt)
#pragma unroll
            for (int ct = 0; ct < 2; ++ct) acc[rt][ct] = (floatx4){0.f, 0.f, 0.f, 0.f};

        u64 aP;
        short8 bP;
        auto loadK = [&](int ks) {
            int row = R0 + rA;
            aP = (row < S_ROWS)
               ? *(const u64*)(Sb + ((size_t)g * S_ROWS + row) * S_COLS2 + ks * 32 + (tid & 3) * 8)
               : 0ull;
            bP = *(const short8*)(tT + (size_t)nB * N_NODES + node0 + ks * 64 + kcB);
        };

        loadK(0);
        for (int ks = 0; ks < 7; ++ks) {
            {
                short8 s0, s1;
#pragma unroll
                for (int j = 0; j < 8; ++j) s0[j] = u8bf((unsigned)(aP >> (4 * j)) & 15u);
#pragma unroll
                for (int j = 0; j < 8; ++j) s1[j] = u8bf((unsigned)(aP >> (32 + 4 * j)) & 15u);
                *(short8*)&As[rA][kcA] = s0;
                *(short8*)&As[rA][kcA + 8] = s1;
                *(short8*)&Bs[nB][kcB] = bP;
            }
            __syncthreads();
            if (ks + 1 < 7) loadK(ks + 1);
#pragma unroll
            for (int k0l = 0; k0l < 64; k0l += 32) {
                short8 af[4], bf[2];
#pragma unroll
                for (int rt = 0; rt < 4; ++rt)
                    af[rt] = *(const short8*)&As[wrow * 64 + rt * 16 + fm][k0l + quad * 8];
#pragma unroll
                for (int ct = 0; ct < 2; ++ct)
                    bf[ct] = *(const short8*)&Bs[wcol + ct * 16 + fm][k0l + quad * 8];
#pragma unroll
                for (int rt = 0; rt < 4; ++rt)
#pragma unroll
                    for (int ct = 0; ct < 2; ++ct)
                        acc[rt][ct] = __builtin_amdgcn_mfma_f32_16x16x32_bf16(
                            af[rt], bf[ct], acc[rt][ct], 0, 0, 0);
            }
            __syncthreads();
        }

#pragma unroll
        for (int rt = 0; rt < 4; ++rt) {
#pragma unroll
            for (int ct = 0; ct < 2; ++ct) {
                int col = wcol + ct * 16 + fm;
                float bv = ba[col];
                int rbase = R0 + wrow * 64 + rt * 16 + quad * 4;
                if (rbase < 400) {
#pragma unroll
                    for (int r = 0; r < 4; ++r) {
                        float v = acc[rt][ct][r] + bv;
                        zg[(size_t)(rbase + r) * 128 + col] = f2bf(v);
                        scol[ct] += v;
                        qcol[ct] += v * v;
                    }
                }
            }
        }
    }

#pragma unroll
    for (int ct = 0; ct < 2; ++ct) {
        scol[ct] += __shfl_xor(scol[ct], 16);
        scol[ct] += __shfl_xor(scol[ct], 32);
        qcol[ct] += __shfl_xor(qcol[ct], 16);
        qcol[ct] += __shfl_xor(qcol[ct], 32);
    }
    if (lane < 16) {
#pragma unroll
        for (int ct = 0; ct < 2; ++ct) { rs[wrow][wc4][ct][lane] = scol[ct]; rq[wrow][wc4][ct][lane] = qcol[ct]; }
    }
    __syncthreads();
    if (tid < 128) {
        int wc = tid >> 5, ct = (tid >> 4) & 1, f = tid & 15;
        float S = 0.f, Q = 0.f;
#pragma unroll
        for (int wr = 0; wr < 4; ++wr) { S += rs[wr][wc][ct][f]; Q += rq[wr][wc][ct][f]; }
        atomicAdd(&psum[bucket * 128 + tid], S);
        atomicAdd(&psq[bucket * 128 + tid], Q);
    }
}

template <int FINAL>
__device__ __forceinline__ void p_post(unsigned char* smem, int g, int tid,
        const us* __restrict__ zg, const float* __restrict__ psum, const float* __restrict__ psq,
        const float* __restrict__ gamma, const float* __restrict__ beta,
        const us* __restrict__ wtb, const float* __restrict__ bb,
        const us* __restrict__ wta_next, us* __restrict__ tT,
        float& pool0, float& pool1) {
    us (*hs)[136] = (us(*)[136])smem;                 // 128x136x2 = 34816
    us (*Bs)[72]  = (us(*)[72])(smem + 34816);        // 18432 -> 53248
    float* coefs  = (float*)(smem + 53248);           // 1024
    int wave = tid >> 6, lane = tid & 63;
    int wrow = wave >> 2;
    int wcol = (wave & 3) * 32;
    int fm = lane & 15, quad = lane >> 4;
    int node0 = g * NPG;

    if (tid < 128) {
        float S = 0.f, Q = 0.f;
#pragma unroll
        for (int b = 0; b < 8; ++b) {
            S += __hip_atomic_load(&psum[b * 128 + tid], __ATOMIC_RELAXED, __HIP_MEMORY_SCOPE_AGENT);
            Q += __hip_atomic_load(&psq[b * 128 + tid], __ATOMIC_RELAXED, __HIP_MEMORY_SCOPE_AGENT);
        }
        float invn = 1.0f / (float)N_NODES;
        float mu = S * invn;
        float var = Q * invn - mu * mu;
        float a = gamma[tid] * rsqrtf(var + BN_EPS);
        coefs[tid] = a;
        coefs[128 + tid] = beta[tid] - a * mu;
    }
    __syncthreads();

    const int rA = tid >> 3, kcA = (tid & 7) * 8;     // 128 rows x 64k; 8 us/thread
    const int nB = tid >> 3, kcB = (tid & 7) * 8;

    for (int R0 = 0; R0 < 400; R0 += 128) {
        floatx4 acc[2][2];
#pragma unroll
        for (int rt = 0; rt < 2; ++rt)
#pragma unroll
            for (int ct = 0; ct < 2; ++ct) acc[rt][ct] = (floatx4){0.f, 0.f, 0.f, 0.f};

        short8 aP, bP;
        auto loadK1 = [&](int ks) {
            int row = R0 + rA;
            if (row < 400) aP = *(const short8*)(zg + (size_t)row * 128 + ks * 64 + kcA);
            else { short8 zz = {0,0,0,0,0,0,0,0}; aP = zz; }
            bP = *(const short8*)(wtb + (size_t)nB * 128 + ks * 64 + kcB);
        };

        loadK1(0);
        for (int ks = 0; ks < 2; ++ks) {
            {
                int kg = ks * 64 + kcA;
                short8 s0;
#pragma unroll
                for (int j = 0; j < 8; ++j) {
                    float v = fmaxf(coefs[kg + j] * bf2f((unsigned short)aP[j]) + coefs[128 + kg + j], 0.f);
                    s0[j] = (short)f2bf(v);
                }
                *(short8*)&hs[rA][kcA] = s0;
                *(short8*)&Bs[nB][kcB] = bP;
            }
            __syncthreads();
            if (ks + 1 < 2) loadK1(ks + 1);
#pragma unroll
            for (int k0l = 0; k0l < 64; k0l += 32) {
                short8 af[2], bf[2];
#pragma unroll
                for (int rt = 0; rt < 2; ++rt)
                    af[rt] = *(const short8*)&hs[wrow * 32 + rt * 16 + fm][k0l + quad * 8];
#pragma unroll
                for (int ct = 0; ct < 2; ++ct)
                    bf[ct] = *(const short8*)&Bs[wcol + ct * 16 + fm][k0l + quad * 8];
#pragma unroll
                for (int rt = 0; rt < 2; ++rt)
#pragma unroll
                    for (int ct = 0; ct < 2; ++ct)
                        acc[rt][ct] = __builtin_amdgcn_mfma_f32_16x16x32_bf16(
                            af[rt], bf[ct], acc[rt][ct], 0, 0, 0);
            }
            __syncthreads();
        }

        if (FINAL) {
#pragma unroll
            for (int rt = 0; rt < 2; ++rt)
#pragma unroll
                for (int ct = 0; ct < 2; ++ct) {
                    int col = wcol + ct * 16 + fm;
                    float bv = bb[col];
                    int rbase = R0 + wrow * 32 + rt * 16 + quad * 4;
                    if (rbase < 400) {
                        float s = 0.f;
#pragma unroll
                        for (int r = 0; r < 4; ++r) s += fmaxf(acc[rt][ct][r] + bv, 0.f);
                        if (ct == 0) pool0 += s; else pool1 += s;
                    }
                }
            continue;
        }

        // h -> hs (cols 0..127; phase-1 A data dead)
#pragma unroll
        for (int rt = 0; rt < 2; ++rt)
#pragma unroll
            for (int ct = 0; ct < 2; ++ct) {
                int col = wcol + ct * 16 + fm;
                float bv = bb[col];
                int rbase = wrow * 32 + rt * 16 + quad * 4;
#pragma unroll
                for (int r = 0; r < 4; ++r)
                    hs[rbase + r][col] = f2bf(fmaxf(acc[rt][ct][r] + bv, 0.f));
            }
        __syncthreads();

        // phase 2: t' = h @ wta_next
#pragma unroll
        for (int rt = 0; rt < 2; ++rt)
#pragma unroll
            for (int ct = 0; ct < 2; ++ct) acc[rt][ct] = (floatx4){0.f, 0.f, 0.f, 0.f};

        for (int ks = 0; ks < 2; ++ks) {
            *(short8*)&Bs[nB][kcB] = *(const short8*)(wta_next + (size_t)nB * 128 + ks * 64 + kcB);
            __syncthreads();
#pragma unroll
            for (int k0l = 0; k0l < 64; k0l += 32) {
                short8 af[2], bf[2];
#pragma unroll
                for (int rt = 0; rt < 2; ++rt)
                    af[rt] = *(const short8*)&hs[wrow * 32 + rt * 16 + fm][ks * 64 + k0l + quad * 8];
#pragma unroll
                for (int ct = 0; ct < 2; ++ct)
                    bf[ct] = *(const short8*)&Bs[wcol + ct * 16 + fm][k0l + quad * 8];
#pragma unroll
                for (int rt = 0; rt < 2; ++rt)
#pragma unroll
                    for (int ct = 0; ct < 2; ++ct)
                        acc[rt][ct] = __builtin_amdgcn_mfma_f32_16x16x32_bf16(
                            af[rt], bf[ct], acc[rt][ct], 0, 0, 0);
            }
            __syncthreads();
        }

#pragma unroll
        for (int rt = 0; rt < 2; ++rt)
#pragma unroll
            for (int ct = 0; ct < 2; ++ct) {
                int col = wcol + ct * 16 + fm;
                int row0 = R0 + wrow * 32 + rt * 16 + quad * 4;
                if (row0 < 400) {
                    ushort4 o;
#pragma unroll
                    for (int r = 0; r < 4; ++r) ((unsigned short*)&o)[r] = f2bf(acc[rt][ct][r]);
                    *(ushort4*)&tT[(size_t)col * N_NODES + node0 + row0] = o;
                }
            }
        __syncthreads();   // hs reused next M-iter
    }
}

__global__ __launch_bounds__(1024, 4) void persist_gnn(
        const unsigned char* __restrict__ Sb, us* __restrict__ tT, us* __restrict__ z,
        float* __restrict__ pstat,
        const us* __restrict__ wtb0, const us* __restrict__ wta1,
        const us* __restrict__ wtb1, const us* __restrict__ wta2,
        const us* __restrict__ wtb2,
        const float* __restrict__ ba0, const float* __restrict__ ba1, const float* __restrict__ ba2,
        const float* __restrict__ gg0, const float* __restrict__ be0, const float* __restrict__ bbias0,
        const float* __restrict__ gg1, const float* __restrict__ be1, const float* __restrict__ bbias1,
        const float* __restrict__ gg2, const float* __restrict__ be2, const float* __restrict__ bbias2,
        const float* __restrict__ wfa, const float* __restrict__ bfa,
        const float* __restrict__ wfb, const float* __restrict__ bfb,
        unsigned* __restrict__ bar, float* __restrict__ out) {
    __shared__ __align__(16) unsigned char smem[59392];
    int g = blockIdx.x, tid = threadIdx.x;
    int wave = tid >> 6, lane = tid & 63;
    int wrow = wave >> 2, wc4 = wave & 3;
    us* zg = z + (size_t)g * NPG * 128;
    float pool0 = 0.f, pool1 = 0.f;

    p_agg(smem, g, tid, Sb, tT, ba0, zg, pstat + 0, pstat + 1024, g & 7);
    gbar(bar, 64);
    p_post<0>(smem, g, tid, zg, pstat + 0, pstat + 1024, gg0, be0, wtb0, bbias0, wta1, tT, pool0, pool1);
    __syncthreads();

    p_agg(smem, g, tid, Sb, tT, ba1, zg, pstat + 2048, pstat + 3072, g & 7);
    gbar(bar, 128);
    p_post<0>(smem, g, tid, zg, pstat + 2048, pstat + 3072, gg1, be1, wtb1, bbias1, wta2, tT, pool0, pool1);
    __syncthreads();

    p_agg(smem, g, tid, Sb, tT, ba2, zg, pstat + 4096, pstat + 5120, g & 7);
    gbar(bar, 192);
    p_post<1>(smem, g, tid, zg, pstat + 4096, pstat + 5120, gg2, be2, wtb2, bbias2, nullptr, tT, pool0, pool1);
    __syncthreads();

    // pooled reduce (block-local)
    float* pl = (float*)smem;                                    // 512
    float (*red)[4][2][16] = (float(*)[4][2][16])(smem + 512);   // 2048
    pool0 += __shfl_xor(pool0, 16); pool0 += __shfl_xor(pool0, 32);
    pool1 += __shfl_xor(pool1, 16); pool1 += __shfl_xor(pool1, 32);
    if (lane < 16) { red[wrow][wc4][0][lane] = pool0; red[wrow][wc4][1][lane] = pool1; }
    __syncthreads();
    if (tid < 128) {
        int wc = tid >> 5, ct = (tid >> 4) & 1, f = tid & 15;
        float s = 0.f;
#pragma unroll
        for (int wr = 0; wr < 4; ++wr) s += red[wr][wc][ct][f];
        pl[tid] = s;
    }
    __syncthreads();

    // head (block-local)
    float* o0 = (float*)(smem + 512);
    float* o1 = (float*)(smem + 1024);
    if (tid < 128) {
        int f = tid;
        float a = bfa[f];
        for (int k = 0; k < 128; ++k) a += pl[k] * wfa[k * 128 + f];
        float p2 = fmaxf(a, 0.f);
        o0[f] = p2 * wfb[f * 2 + 0];
        o1[f] = p2 * wfb[f * 2 + 1];
    }
    __syncthreads();
    if (tid == 0) {
        float a0 = bfb[0], a1 = bfb[1];
#pragma unroll
        for (int k = 0; k < 128; ++k) { a0 += o0[k]; a1 += o1[k]; }
        out[g * 2 + 0] = a0;
        out[g * 2 + 1] = a1;
    }
}

// ---------------- launch ----------------

extern "C" void kernel_launch(void* const* d_in, const int* in_sizes, int n_in,
                              void* d_out, int out_size, void* d_ws, size_t ws_size,
                              hipStream_t stream) {
    const float* x   = (const float*)d_in[0];
    const int* ei    = (const int*)d_in[1];
    const int* gid   = (const int*)d_in[3];
    const float* ge  = (const float*)d_in[4];
    const float* he  = (const float*)d_in[5];
    const float* wa[3] = {(const float*)d_in[6],  (const float*)d_in[12], (const float*)d_in[18]};
    const float* ba[3] = {(const float*)d_in[7],  (const float*)d_in[13], (const float*)d_in[19]};
    const float* gg[3] = {(const float*)d_in[8],  (const float*)d_in[14], (const float*)d_in[20]};
    const float* bb_[3]= {(const float*)d_in[9],  (const float*)d_in[15], (const float*)d_in[21]};
    const float* wb[3] = {(const float*)d_in[10], (const float*)d_in[16], (const float*)d_in[22]};
    const float* bbias[3] = {(const float*)d_in[11], (const float*)d_in[17], (const float*)d_in[23]};
    const float* wfa = (const float*)d_in[24];
    const float* bfa = (const float*)d_in[25];
    const float* wfb = (const float*)d_in[26];
    const float* bfb = (const float*)d_in[27];
    float* out = (float*)d_out;

    char* ws = (char*)d_ws;
    size_t o = 0;
    auto alloc = [&](size_t bytes) { char* p = ws + o; o += (bytes + 255) & ~(size_t)255; return p; };
    us* tT = (us*)alloc((size_t)128 * N_NODES * 2 + 1024);
    us* z  = (us*)alloc((size_t)N_NODES * 128 * 2);
    unsigned char* Sb  = (unsigned char*)alloc((size_t)NB * S_ROWS * S_COLS2);
    float* pstat = (float*)alloc((3 * 2048 + 8192) * 4);
    us* wt0  = (us*)alloc(128 * K0PAD * 2);
    us* wta1 = (us*)alloc(128 * 128 * 2);
    us* wta2 = (us*)alloc(128 * 128 * 2);
    us* wtb0 = (us*)alloc(128 * 128 * 2);
    us* wtb1 = (us*)alloc(128 * 128 * 2);
    us* wtb2 = (us*)alloc(128 * 128 * 2);
    unsigned* bar = (unsigned*)alloc(256);
    (void)ws_size; (void)in_sizes; (void)n_in; (void)out_size;

    hipMemsetAsync(bar, 0, 256, stream);

    prep<<<256 + 544, 256, 0, stream>>>(ei, ei + NE, Sb,
                                        wa[0], wa[1], wa[2], wb[0], wb[1], wb[2],
                                        wt0, wta1, wta2, wtb0, wtb1, wtb2, pstat, tT);

    gemm_embed64<<<400, 256, 0, stream>>>(x, wt0, wa[0], gid, ge, he, tT);

    persist_gnn<<<64, 1024, 0, stream>>>(Sb, tT, z, pstat,
                                         wtb0, wta1, wtb1, wta2, wtb2,
                                         ba[0], ba[1], ba[2],
                                         gg[0], bb_[0], bbias[0],
                                         gg[1], bb_[1], bbias[1],
                                         gg[2], bb_[2], bbias[2],
                                         wfa, bfa, wfb, bfb,
                                         bar, out);
}

// Round 4
// 283.552 us; speedup vs baseline: 2.6091x; 1.2259x over previous
//
#include <hip/hip_runtime.h>

#define N_NODES 25600
#define F_IN 400
#define NE 512000
#define NB 64
#define NPG 400
#define EPG 8000
#define BN_EPS 1e-5f
#define NBLK 256

typedef __attribute__((ext_vector_type(8))) short short8;
typedef __attribute__((ext_vector_type(4))) float floatx4;
typedef unsigned short us;
typedef unsigned long long u64;

__device__ __forceinline__ unsigned short f2bf(float f) {
    unsigned int u = __float_as_uint(f);
    u += 0x7FFF + ((u >> 16) & 1);   // RNE
    return (unsigned short)(u >> 16);
}
__device__ __forceinline__ float bf2f(unsigned short s) {
    return __uint_as_float((unsigned int)s << 16);
}
// exact for integers 0..255
__device__ __forceinline__ short u8bf(unsigned v) {
    return (short)(__float_as_uint((float)v) >> 16);
}
// agent-scope (coherence-point) 8B ops: bypass non-coherent per-XCD L2s, served by L3.
__device__ __forceinline__ u64 ald64(const void* p) {
    return __hip_atomic_load((const u64*)p, __ATOMIC_RELAXED, __HIP_MEMORY_SCOPE_AGENT);
}
__device__ __forceinline__ void ast64(void* p, u64 v) {
    __hip_atomic_store((u64*)p, v, __ATOMIC_RELAXED, __HIP_MEMORY_SCOPE_AGENT);
}
__device__ __forceinline__ u64 pk4(unsigned short a, unsigned short b, unsigned short c, unsigned short d) {
    return (u64)a | ((u64)b << 16) | ((u64)c << 32) | ((u64)d << 48);
}

// fence-free grid barrier (all shared data moves via coherence-point atomics)
__device__ __forceinline__ void gsync(unsigned* bar, unsigned tgt) {
    __syncthreads();
    if (threadIdx.x == 0) {
        __hip_atomic_fetch_add(bar, 1u, __ATOMIC_RELAXED, __HIP_MEMORY_SCOPE_AGENT);
        while (__hip_atomic_load(bar, __ATOMIC_RELAXED, __HIP_MEMORY_SCOPE_AGENT) < tgt)
            __builtin_amdgcn_s_sleep(8);
        asm volatile("" ::: "memory");
    }
    __syncthreads();
}

// LDS plan (120832 B total):
//  prep : cnt32 44800 @0
//  embed: As[128][72] @0 (18432) | Bs[128][72] @18432 | Wex[4][128] @36864 (2048)
//  agg  : Bpanel[128][456] @0 (116736) ; epilogue z_lds[128][136] @0 (34816, B dead) ;
//         rs/rq @116736 (4096)
//  post : z_lds @0 | coefs @34816 (1024) | hs[128][136] @35840 (34816) | Bw[128][72] @70656 (18432)
//  final: red @89088 (2048) ; head: pl/o0/o1 @0

// ---------------- phase: prep (adjacency slab bf16, weight transposes, zero stats) ----------------

__device__ __forceinline__ void ph_prep(unsigned char* sm, int bid, int tid,
        const int* __restrict__ src, const int* __restrict__ dst, us* __restrict__ SbBF,
        const float* __restrict__ wa0, const float* __restrict__ wa1, const float* __restrict__ wa2,
        const float* __restrict__ wb0, const float* __restrict__ wb1, const float* __restrict__ wb2,
        us* __restrict__ wt0, us* __restrict__ wtb0, us* __restrict__ wta1,
        us* __restrict__ wtb1, us* __restrict__ wta2, us* __restrict__ wtb2,
        float* __restrict__ pstat, us* __restrict__ tT) {
    int g = bid >> 2, q = bid & 3;
    int r0 = q * 112;
    int* cnt = (int*)sm;                      // 112*400 bytes as 11200 ints
    for (int i = tid; i < 11200; i += 1024) cnt[i] = 0;
    __syncthreads();
    int ebase = g * EPG, nbase = g * NPG;
    for (int e = tid; e < EPG; e += 1024) {
        int d = dst[ebase + e] - nbase;
        int dr = d - r0;
        if ((unsigned)dr < 112u) {
            int s = src[ebase + e] - nbase;
            int idx = dr * NPG + s;
            atomicAdd(&cnt[idx >> 2], (int)(1u << ((idx & 3) * 8)));
        }
    }
    __syncthreads();
    const unsigned char* cb = (const unsigned char*)cnt;
    // bf16 slab rows [r0, r0+112), cols 0..447 (cols>=400 zero); block-private
    for (int i = tid; i < 112 * 112; i += 1024) {
        int rr = i / 112, c4 = (i % 112) * 4;
        int R = r0 + rr;
        ushort4 o;
#pragma unroll
        for (int j = 0; j < 4; ++j) {
            int c = c4 + j;
            unsigned v = (R < NPG && c < NPG) ? (unsigned)cb[rr * NPG + c] + (c == R ? 1u : 0u) : 0u;
            ((unsigned short*)&o)[j] = (unsigned short)u8bf(v);
        }
        *(ushort4*)&SbBF[((size_t)g * 512 + R) * 448 + c4] = o;
    }
    if (q == 3) {   // zero pad rows 448..511 (read by masked A-fragments)
        for (int i = tid; i < 64 * 112; i += 1024) {
            int rr = 448 + i / 112, c4 = (i % 112) * 4;
            *(u64*)&SbBF[((size_t)g * 512 + rr) * 448 + c4] = 0ull;
        }
    }
    // distributed one-shot jobs (blocks 0..63), all via coherence-point stores
    if (bid < 64) {
        int idx = bid * 1024 + tid;          // 0..65535
        if (idx < 14336) {                   // wt0: [n=128][k=448] bf16, zero-padded K
            int n = idx / 112, k0 = (idx % 112) * 4;
            unsigned short o[4];
#pragma unroll
            for (int j = 0; j < 4; ++j) {
                int k = k0 + j;
                o[j] = (k < 400) ? f2bf(wa0[(size_t)k * 128 + n]) : (unsigned short)0;
            }
            ast64(&wt0[(size_t)n * 448 + k0], pk4(o[0], o[1], o[2], o[3]));
        } else if (idx < 14336 + 20480) {    // 5 x [n=128][k=128] transposes
            int r2 = idx - 14336;
            int m = r2 >> 12, qi = r2 & 4095;
            int r = qi * 4, n = r >> 7, k = r & 127;
            const float* smat = (m == 0) ? wb0 : (m == 1) ? wa1 : (m == 2) ? wb1 : (m == 3) ? wa2 : wb2;
            us* dmat = (m == 0) ? wtb0 : (m == 1) ? wta1 : (m == 2) ? wtb1 : (m == 3) ? wta2 : wtb2;
            unsigned short o[4];
#pragma unroll
            for (int j = 0; j < 4; ++j) o[j] = f2bf(smat[(size_t)(k + j) * 128 + n]);
            ast64(&dmat[r], pk4(o[0], o[1], o[2], o[3]));
        } else if (idx < 34816 + 1792) {     // zero pstat (psum/psq x3 + pooled) = 14336 f32
            int qi = idx - 34816;
            ast64(&((u64*)pstat)[qi], 0ull);
        } else if (idx < 36608 + 128) {      // zero tT tail slack (512 us)
            int qi = idx - 36608;
            ast64(&tT[(size_t)128 * N_NODES + qi * 4], 0ull);
        }
    }
}

// ---------------- phase: embed  tT = ([x | ge | he] @ W0a)^T ----------------

__device__ __forceinline__ void ph_embed(unsigned char* sm, int bid, int tid,
        const float* __restrict__ x, const us* __restrict__ wt0, const float* __restrict__ wa0,
        const int* __restrict__ gid, const float* __restrict__ ge, const float* __restrict__ he,
        us* __restrict__ tT) {
    us (*As)[72] = (us(*)[72])sm;
    us (*Bs)[72] = (us(*)[72])(sm + 18432);
    float (*Wex)[128] = (float(*)[128])(sm + 36864);
    int nb = bid * 100;
    int wave = tid >> 6, lane = tid & 63;
    int wrow = wave >> 2, wc4 = wave & 3;
    int fm = lane & 15, quad = lane >> 4;

    for (int i = tid; i < 512; i += 1024)
        Wex[i >> 7][i & 127] = wa0[(size_t)(400 + (i >> 7)) * 128 + (i & 127)];

    floatx4 acc[2][2];
#pragma unroll
    for (int rt = 0; rt < 2; ++rt)
#pragma unroll
        for (int ct = 0; ct < 2; ++ct) acc[rt][ct] = (floatx4){0.f, 0.f, 0.f, 0.f};

    const int rA = tid >> 3, kcA = (tid & 7) * 8;    // 128 rows x 64 k, 8 elems/thread
    float v[8];
    short8 bP;
    auto loadK = [&](int ks) {
        int kg = ks * 64 + kcA;
        if (rA < 100) {
            const float* ar = x + (size_t)(nb + rA) * F_IN;
            if (kg + 7 < 400) {
                float4 a = *(const float4*)(ar + kg);
                float4 b = *(const float4*)(ar + kg + 4);
                v[0] = a.x; v[1] = a.y; v[2] = a.z; v[3] = a.w;
                v[4] = b.x; v[5] = b.y; v[6] = b.z; v[7] = b.w;
            } else {
#pragma unroll
                for (int j = 0; j < 8; ++j) v[j] = (kg + j < 400) ? ar[kg + j] : 0.f;
            }
        } else {
#pragma unroll
            for (int j = 0; j < 8; ++j) v[j] = 0.f;
        }
        bP = *(const short8*)(wt0 + (size_t)rA * 448 + kg);
    };

    loadK(0);
    for (int ks = 0; ks < 7; ++ks) {
        {
            short8 s;
#pragma unroll
            for (int j = 0; j < 8; ++j) s[j] = (short)f2bf(v[j]);
            *(short8*)&As[rA][kcA] = s;
            *(short8*)&Bs[rA][kcA] = bP;
        }
        __syncthreads();
        if (ks + 1 < 7) loadK(ks + 1);
#pragma unroll
        for (int k0l = 0; k0l < 64; k0l += 32) {
            short8 af[2], bf[2];
#pragma unroll
            for (int rt = 0; rt < 2; ++rt)
                af[rt] = *(const short8*)&As[wrow * 32 + rt * 16 + fm][k0l + quad * 8];
#pragma unroll
            for (int ct = 0; ct < 2; ++ct)
                bf[ct] = *(const short8*)&Bs[wc4 * 32 + ct * 16 + fm][k0l + quad * 8];
#pragma unroll
            for (int rt = 0; rt < 2; ++rt)
#pragma unroll
                for (int ct = 0; ct < 2; ++ct)
                    acc[rt][ct] = __builtin_amdgcn_mfma_f32_16x16x32_bf16(
                        af[rt], bf[ct], acc[rt][ct], 0, 0, 0);
        }
        __syncthreads();
    }

#pragma unroll
    for (int rt = 0; rt < 2; ++rt)
#pragma unroll
        for (int ct = 0; ct < 2; ++ct) {
            int col = wc4 * 32 + ct * 16 + fm;
            int rl0 = wrow * 32 + rt * 16 + quad * 4;
            if (rl0 < 100) {
                unsigned short o[4];
#pragma unroll
                for (int r = 0; r < 4; ++r) {
                    int row = nb + rl0 + r;
                    int gv = gid[row];
                    float vv = acc[rt][ct][r]
                             + ge[gv * 2] * Wex[0][col] + ge[gv * 2 + 1] * Wex[1][col]
                             + he[(row & 1) * 2] * Wex[2][col] + he[(row & 1) * 2 + 1] * Wex[3][col];
                    o[r] = f2bf(vv);
                }
                ast64(&tT[(size_t)col * N_NODES + nb + rl0], pk4(o[0], o[1], o[2], o[3]));
            }
        }
}

// ---------------- phase: agg  z = (S+I)@t + ba ; z stays in LDS; BN partials ----------------

__device__ __forceinline__ void ph_agg(unsigned char* sm, int g, int q, int tid,
        const us* __restrict__ SbBF, const us* __restrict__ tT, const float* __restrict__ ba,
        float* __restrict__ psum, float* __restrict__ psq, int bucket) {
    us (*Bs)[456] = (us(*)[456])sm;                              // full B panel, 116736 B
    us (*zl)[136] = (us(*)[136])sm;                              // epilogue reuse
    float (*rs)[4][2][16] = (float(*)[4][2][16])(sm + 116736);
    float (*rq)[4][2][16] = (float(*)[4][2][16])(sm + 118784);
    int wave = tid >> 6, lane = tid & 63;
    int wrow = wave >> 2, wc4 = wave & 3;
    int fm = lane & 15, quad = lane >> 4;
    int node0 = g * NPG;

    // stage full tT panel (coherence-point loads; k>=400 garbage x zero-A = 0)
    for (int i = tid; i < 14336; i += 1024) {
        int col = i / 112, kq = (i % 112) * 4;
        u64 vv = ald64(tT + (size_t)col * N_NODES + node0 + kq);
        *(u64*)&Bs[col][kq] = vv;
    }
    __syncthreads();

    floatx4 acc[2][2];
#pragma unroll
    for (int rt = 0; rt < 2; ++rt)
#pragma unroll
        for (int ct = 0; ct < 2; ++ct) acc[rt][ct] = (floatx4){0.f, 0.f, 0.f, 0.f};

    const us* abase = SbBF + ((size_t)g * 512 + q * 112) * 448;
    // barrier-free K loop: A per-lane from cached global slab, B from LDS
#pragma unroll
    for (int ks = 0; ks < 7; ++ks) {
#pragma unroll
        for (int k0l = 0; k0l < 64; k0l += 32) {
            short8 af[2], bf[2];
#pragma unroll
            for (int rt = 0; rt < 2; ++rt)
                af[rt] = *(const short8*)(abase + (size_t)(wrow * 32 + rt * 16 + fm) * 448
                                          + ks * 64 + k0l + quad * 8);
#pragma unroll
            for (int ct = 0; ct < 2; ++ct)
                bf[ct] = *(const short8*)&Bs[wc4 * 32 + ct * 16 + fm][ks * 64 + k0l + quad * 8];
#pragma unroll
            for (int rt = 0; rt < 2; ++rt)
#pragma unroll
                for (int ct = 0; ct < 2; ++ct)
                    acc[rt][ct] = __builtin_amdgcn_mfma_f32_16x16x32_bf16(
                        af[rt], bf[ct], acc[rt][ct], 0, 0, 0);
        }
    }
    __syncthreads();   // B panel dead; zl overlays it

    int nrows = (q < 3) ? 112 : 64;
    float sc[2] = {0.f, 0.f}, sq2[2] = {0.f, 0.f};
#pragma unroll
    for (int rt = 0; rt < 2; ++rt)
#pragma unroll
        for (int ct = 0; ct < 2; ++ct) {
            int col = wc4 * 32 + ct * 16 + fm;
            int rl0 = wrow * 32 + rt * 16 + quad * 4;
            if (rl0 < nrows) {
                float bv = ba[col];
#pragma unroll
                for (int r = 0; r < 4; ++r) {
                    float vv = acc[rt][ct][r] + bv;
                    zl[rl0 + r][col] = f2bf(vv);
                    sc[ct] += vv;
                    sq2[ct] += vv * vv;
                }
            }
        }
#pragma unroll
    for (int ct = 0; ct < 2; ++ct) {
        sc[ct] += __shfl_xor(sc[ct], 16);
        sc[ct] += __shfl_xor(sc[ct], 32);
        sq2[ct] += __shfl_xor(sq2[ct], 16);
        sq2[ct] += __shfl_xor(sq2[ct], 32);
    }
    if (lane < 16) {
#pragma unroll
        for (int ct = 0; ct < 2; ++ct) { rs[wrow][wc4][ct][lane] = sc[ct]; rq[wrow][wc4][ct][lane] = sq2[ct]; }
    }
    __syncthreads();
    if (tid < 128) {
        int wc = tid >> 5, ct = (tid >> 4) & 1, f = tid & 15;
        float S = 0.f, Q = 0.f;
#pragma unroll
        for (int wr = 0; wr < 4; ++wr) { S += rs[wr][wc][ct][f]; Q += rq[wr][wc][ct][f]; }
        atomicAdd(&psum[bucket * 128 + tid], S);
        atomicAdd(&psq[bucket * 128 + tid], Q);
    }
}

// ---------------- phase: post  BN + h=relu(relu(affine(z))@wb+bb) [+ t'=h@wa_next | pool] ----------------

template <int FINAL>
__device__ __forceinline__ void ph_post(unsigned char* sm, int g, int q, int tid,
        const float* __restrict__ psum, const float* __restrict__ psq,
        const float* __restrict__ gamma, const float* __restrict__ beta,
        const us* __restrict__ wtb, const float* __restrict__ bb,
        const us* __restrict__ wta_next, us* __restrict__ tT, float& p0, float& p1) {
    us (*zl)[136] = (us(*)[136])sm;
    float* coefs = (float*)(sm + 34816);
    us (*hs)[136] = (us(*)[136])(sm + 35840);
    us (*Bw)[72] = (us(*)[72])(sm + 70656);
    int wave = tid >> 6, lane = tid & 63;
    int wrow = wave >> 2, wc4 = wave & 3;
    int fm = lane & 15, quad = lane >> 4;
    int nrows = (q < 3) ? 112 : 64;
    int nb = g * NPG + q * 112;

    if (tid < 128) {
        float S = 0.f, Q = 0.f;
#pragma unroll
        for (int b = 0; b < 8; ++b) {
            S += __hip_atomic_load(&psum[b * 128 + tid], __ATOMIC_RELAXED, __HIP_MEMORY_SCOPE_AGENT);
            Q += __hip_atomic_load(&psq[b * 128 + tid], __ATOMIC_RELAXED, __HIP_MEMORY_SCOPE_AGENT);
        }
        float invn = 1.0f / (float)N_NODES;
        float mu = S * invn;
        float var = Q * invn - mu * mu;
        float a = gamma[tid] * rsqrtf(var + BN_EPS);
        coefs[tid] = a;
        coefs[128 + tid] = beta[tid] - a * mu;
    }
    __syncthreads();
    // affine+relu in place (garbage rows become finite; masked later)
    for (int i = tid; i < 16384; i += 1024) {
        int rl = i >> 7, col = i & 127;
        float vv = bf2f(zl[rl][col]);
        zl[rl][col] = f2bf(fmaxf(coefs[col] * vv + coefs[128 + col], 0.f));
    }
    __syncthreads();

    floatx4 acc[2][2];
#pragma unroll
    for (int rt = 0; rt < 2; ++rt)
#pragma unroll
        for (int ct = 0; ct < 2; ++ct) acc[rt][ct] = (floatx4){0.f, 0.f, 0.f, 0.f};

    const int nB = tid >> 3, kc = (tid & 7) * 8;
    for (int ks = 0; ks < 2; ++ks) {
        *(short8*)&Bw[nB][kc] = *(const short8*)(wtb + (size_t)nB * 128 + ks * 64 + kc);
        __syncthreads();
#pragma unroll
        for (int k0l = 0; k0l < 64; k0l += 32) {
            short8 af[2], bf[2];
#pragma unroll
            for (int rt = 0; rt < 2; ++rt)
                af[rt] = *(const short8*)&zl[wrow * 32 + rt * 16 + fm][ks * 64 + k0l + quad * 8];
#pragma unroll
            for (int ct = 0; ct < 2; ++ct)
                bf[ct] = *(const short8*)&Bw[wc4 * 32 + ct * 16 + fm][k0l + quad * 8];
#pragma unroll
            for (int rt = 0; rt < 2; ++rt)
#pragma unroll
                for (int ct = 0; ct < 2; ++ct)
                    acc[rt][ct] = __builtin_amdgcn_mfma_f32_16x16x32_bf16(
                        af[rt], bf[ct], acc[rt][ct], 0, 0, 0);
        }
        __syncthreads();
    }

    if (FINAL) {
#pragma unroll
        for (int rt = 0; rt < 2; ++rt)
#pragma unroll
            for (int ct = 0; ct < 2; ++ct) {
                int col = wc4 * 32 + ct * 16 + fm;
                int rl0 = wrow * 32 + rt * 16 + quad * 4;
                if (rl0 < nrows) {
                    float bv = bb[col];
                    float s = 0.f;
#pragma unroll
                    for (int r = 0; r < 4; ++r) s += fmaxf(acc[rt][ct][r] + bv, 0.f);
                    if (ct == 0) p0 += s; else p1 += s;
                }
            }
        return;
    }

#pragma unroll
    for (int rt = 0; rt < 2; ++rt)
#pragma unroll
        for (int ct = 0; ct < 2; ++ct) {
            int col = wc4 * 32 + ct * 16 + fm;
            float bv = bb[col];
            int rl0 = wrow * 32 + rt * 16 + quad * 4;
#pragma unroll
            for (int r = 0; r < 4; ++r)
                hs[rl0 + r][col] = f2bf(fmaxf(acc[rt][ct][r] + bv, 0.f));
        }
    __syncthreads();

#pragma unroll
    for (int rt = 0; rt < 2; ++rt)
#pragma unroll
        for (int ct = 0; ct < 2; ++ct) acc[rt][ct] = (floatx4){0.f, 0.f, 0.f, 0.f};

    for (int ks = 0; ks < 2; ++ks) {
        *(short8*)&Bw[nB][kc] = *(const short8*)(wta_next + (size_t)nB * 128 + ks * 64 + kc);
        __syncthreads();
#pragma unroll
        for (int k0l = 0; k0l < 64; k0l += 32) {
            short8 af[2], bf[2];
#pragma unroll
            for (int rt = 0; rt < 2; ++rt)
                af[rt] = *(const short8*)&hs[wrow * 32 + rt * 16 + fm][ks * 64 + k0l + quad * 8];
#pragma unroll
            for (int ct = 0; ct < 2; ++ct)
                bf[ct] = *(const short8*)&Bw[wc4 * 32 + ct * 16 + fm][k0l + quad * 8];
#pragma unroll
            for (int rt = 0; rt < 2; ++rt)
#pragma unroll
                for (int ct = 0; ct < 2; ++ct)
                    acc[rt][ct] = __builtin_amdgcn_mfma_f32_16x16x32_bf16(
                        af[rt], bf[ct], acc[rt][ct], 0, 0, 0);
        }
        __syncthreads();
    }

#pragma unroll
    for (int rt = 0; rt < 2; ++rt)
#pragma unroll
        for (int ct = 0; ct < 2; ++ct) {
            int col = wc4 * 32 + ct * 16 + fm;
            int rl0 = wrow * 32 + rt * 16 + quad * 4;
            if (rl0 < nrows) {
                unsigned short o[4];
#pragma unroll
                for (int r = 0; r < 4; ++r) o[r] = f2bf(acc[rt][ct][r]);
                ast64(&tT[(size_t)col * N_NODES + nb + rl0], pk4(o[0], o[1], o[2], o[3]));
            }
        }
}

// ---------------- the single persistent kernel ----------------

__global__ __launch_bounds__(1024, 4) void persist_all(
        const float* __restrict__ x, const int* __restrict__ esrc, const int* __restrict__ edst,
        const int* __restrict__ gid, const float* __restrict__ ge, const float* __restrict__ he,
        const float* __restrict__ wa0, const float* __restrict__ ba0, const float* __restrict__ gg0,
        const float* __restrict__ be0, const float* __restrict__ wb0, const float* __restrict__ bbias0,
        const float* __restrict__ wa1, const float* __restrict__ ba1, const float* __restrict__ gg1,
        const float* __restrict__ be1, const float* __restrict__ wb1, const float* __restrict__ bbias1,
        const float* __restrict__ wa2, const float* __restrict__ ba2, const float* __restrict__ gg2,
        const float* __restrict__ be2, const float* __restrict__ wb2, const float* __restrict__ bbias2,
        const float* __restrict__ wfa, const float* __restrict__ bfa,
        const float* __restrict__ wfb, const float* __restrict__ bfb,
        us* __restrict__ tT, us* __restrict__ SbBF, float* __restrict__ pstat,
        us* __restrict__ wt0, us* __restrict__ wtb0, us* __restrict__ wta1,
        us* __restrict__ wtb1, us* __restrict__ wta2, us* __restrict__ wtb2,
        unsigned* __restrict__ bar, float* __restrict__ out) {
    __shared__ __align__(16) unsigned char sm[120832];
    int bid = blockIdx.x, tid = threadIdx.x;
    int g = bid >> 2, q = bid & 3;
    float* pooled = pstat + 6144;
    float p0 = 0.f, p1 = 0.f;

    ph_prep(sm, bid, tid, esrc, edst, SbBF, wa0, wa1, wa2, wb0, wb1, wb2,
            wt0, wtb0, wta1, wtb1, wta2, wtb2, pstat, tT);
    gsync(bar, 1 * NBLK);
    ph_embed(sm, bid, tid, x, wt0, wa0, gid, ge, he, tT);
    gsync(bar, 2 * NBLK);

    ph_agg(sm, g, q, tid, SbBF, tT, ba0, pstat + 0, pstat + 1024, bid & 7);
    gsync(bar, 3 * NBLK);
    ph_post<0>(sm, g, q, tid, pstat + 0, pstat + 1024, gg0, be0, wtb0, bbias0, wta1, tT, p0, p1);
    gsync(bar, 4 * NBLK);

    ph_agg(sm, g, q, tid, SbBF, tT, ba1, pstat + 2048, pstat + 3072, bid & 7);
    gsync(bar, 5 * NBLK);
    ph_post<0>(sm, g, q, tid, pstat + 2048, pstat + 3072, gg1, be1, wtb1, bbias1, wta2, tT, p0, p1);
    gsync(bar, 6 * NBLK);

    ph_agg(sm, g, q, tid, SbBF, tT, ba2, pstat + 4096, pstat + 5120, bid & 7);
    gsync(bar, 7 * NBLK);
    ph_post<1>(sm, g, q, tid, pstat + 4096, pstat + 5120, gg2, be2, wtb2, bbias2, nullptr, tT, p0, p1);

    // per-graph pool: reduce within block, then coherence-point atomics
    {
        int wave = tid >> 6, lane = tid & 63;
        int wrow = wave >> 2, wc4 = wave & 3;
        float (*red)[4][2][16] = (float(*)[4][2][16])(sm + 89088);
        p0 += __shfl_xor(p0, 16); p0 += __shfl_xor(p0, 32);
        p1 += __shfl_xor(p1, 16); p1 += __shfl_xor(p1, 32);
        __syncthreads();
        if (lane < 16) { red[wrow][wc4][0][lane] = p0; red[wrow][wc4][1][lane] = p1; }
        __syncthreads();
        if (tid < 128) {
            int wc = tid >> 5, ct = (tid >> 4) & 1, f = tid & 15;
            float s = 0.f;
#pragma unroll
            for (int wr = 0; wr < 4; ++wr) s += red[wr][wc][ct][f];
            atomicAdd(&pooled[g * 128 + tid], s);
        }
    }
    gsync(bar, 8 * NBLK);

    // head: one block per graph
    if ((bid & 3) == 0) {
        float* pl = (float*)sm;
        float* o0 = pl + 128;
        float* o1 = pl + 256;
        if (tid < 128) {
            unsigned uv = __hip_atomic_load((const unsigned*)&pooled[g * 128 + tid],
                                            __ATOMIC_RELAXED, __HIP_MEMORY_SCOPE_AGENT);
            pl[tid] = __uint_as_float(uv);
        }
        __syncthreads();
        if (tid < 128) {
            float a = bfa[tid];
            for (int k = 0; k < 128; ++k) a += pl[k] * wfa[k * 128 + tid];
            float p2 = fmaxf(a, 0.f);
            o0[tid] = p2 * wfb[tid * 2 + 0];
            o1[tid] = p2 * wfb[tid * 2 + 1];
        }
        __syncthreads();
        if (tid == 0) {
            float a0 = bfb[0], a1 = bfb[1];
#pragma unroll
            for (int k = 0; k < 128; ++k) { a0 += o0[k]; a1 += o1[k]; }
            out[g * 2 + 0] = a0;
            out[g * 2 + 1] = a1;
        }
    }
}

// ---------------- launch ----------------

extern "C" void kernel_launch(void* const* d_in, const int* in_sizes, int n_in,
                              void* d_out, int out_size, void* d_ws, size_t ws_size,
                              hipStream_t stream) {
    const float* x   = (const float*)d_in[0];
    const int* ei    = (const int*)d_in[1];
    const int* gid   = (const int*)d_in[3];
    const float* ge  = (const float*)d_in[4];
    const float* he  = (const float*)d_in[5];
    float* out = (float*)d_out;

    char* ws = (char*)d_ws;
    size_t o = 0;
    auto alloc = [&](size_t bytes) { char* p = ws + o; o += (bytes + 255) & ~(size_t)255; return p; };
    us* tT   = (us*)alloc((size_t)128 * N_NODES * 2 + 1024);
    us* SbBF = (us*)alloc((size_t)NB * 512 * 448 * 2);
    float* pstat = (float*)alloc(14336 * 4);
    us* wt0  = (us*)alloc(128 * 448 * 2);
    us* wtb0 = (us*)alloc(128 * 128 * 2);
    us* wta1 = (us*)alloc(128 * 128 * 2);
    us* wtb1 = (us*)alloc(128 * 128 * 2);
    us* wta2 = (us*)alloc(128 * 128 * 2);
    us* wtb2 = (us*)alloc(128 * 128 * 2);
    unsigned* bar = (unsigned*)alloc(256);
    (void)ws_size; (void)in_sizes; (void)n_in; (void)out_size;

    hipMemsetAsync(bar, 0, 256, stream);

    persist_all<<<NBLK, 1024, 0, stream>>>(
        x, ei, ei + NE, gid, ge, he,
        (const float*)d_in[6],  (const float*)d_in[7],  (const float*)d_in[8],
        (const float*)d_in[9],  (const float*)d_in[10], (const float*)d_in[11],
        (const float*)d_in[12], (const float*)d_in[13], (const float*)d_in[14],
        (const float*)d_in[15], (const float*)d_in[16], (const float*)d_in[17],
        (const float*)d_in[18], (const float*)d_in[19], (const float*)d_in[20],
        (const float*)d_in[21], (const float*)d_in[22], (const float*)d_in[23],
        (const float*)d_in[24], (const float*)d_in[25],
        (const float*)d_in[26], (const float*)d_in[27],
        tT, SbBF, pstat, wt0, wtb0, wta1, wtb1, wta2, wtb2,
        bar, out);
}

// Round 5
// 244.604 us; speedup vs baseline: 3.0245x; 1.1592x over previous
//
#include <hip/hip_runtime.h>

#define N_NODES 25600
#define F_IN 400
#define NE 512000
#define NB 64
#define NPG 400
#define EPG 8000
#define BN_EPS 1e-5f
#define NBLK 256

typedef __attribute__((ext_vector_type(8))) short short8;
typedef __attribute__((ext_vector_type(4))) float floatx4;
typedef unsigned short us;
typedef unsigned long long u64;

__device__ __forceinline__ unsigned short f2bf(float f) {
    unsigned int u = __float_as_uint(f);
    u += 0x7FFF + ((u >> 16) & 1);   // RNE
    return (unsigned short)(u >> 16);
}
__device__ __forceinline__ float bf2f(unsigned short s) {
    return __uint_as_float((unsigned int)s << 16);
}
// exact for integers 0..255
__device__ __forceinline__ short u8bf(unsigned v) {
    return (short)(__float_as_uint((float)v) >> 16);
}
// agent-scope (coherence-point) ops: stores land at L3, bypassing the writer's non-coherent L2.
__device__ __forceinline__ void ast64(void* p, u64 v) {
    __hip_atomic_store((u64*)p, v, __ATOMIC_RELAXED, __HIP_MEMORY_SCOPE_AGENT);
}
__device__ __forceinline__ u64 pk4(unsigned short a, unsigned short b, unsigned short c, unsigned short d) {
    return (u64)a | ((u64)b << 16) | ((u64)c << 32) | ((u64)d << 48);
}

// ---- hierarchical grid barrier: 16 leaves x 16 blocks + root; ~32 serialized RMWs total ----
__device__ __forceinline__ void gsync_tree(unsigned* bar, int bid, int phase) {
    __syncthreads();                       // drains vmcnt: all prior stores/atomics complete
    if (threadIdx.x == 0) {
        unsigned* leaf = bar + 32 + (bid >> 4) * 32;        // 128B-spaced lines
        unsigned v = __hip_atomic_fetch_add(leaf, 1u, __ATOMIC_RELAXED, __HIP_MEMORY_SCOPE_AGENT);
        if (v == (unsigned)(phase * 16 - 1))
            __hip_atomic_fetch_add(bar, 1u, __ATOMIC_RELAXED, __HIP_MEMORY_SCOPE_AGENT);
        while (__hip_atomic_load(bar, __ATOMIC_RELAXED, __HIP_MEMORY_SCOPE_AGENT) < (unsigned)(phase * 16))
            __builtin_amdgcn_s_sleep(16);
        asm volatile("" ::: "memory");
    }
    __syncthreads();
}

// ---- per-graph micro-barrier: only the 4 blocks of one graph (4 RMWs) ----
__device__ __forceinline__ void gbar4(unsigned* gc, int stage) {
    __syncthreads();
    if (threadIdx.x == 0) {
        __hip_atomic_fetch_add(gc, 1u, __ATOMIC_RELAXED, __HIP_MEMORY_SCOPE_AGENT);
        while (__hip_atomic_load(gc, __ATOMIC_RELAXED, __HIP_MEMORY_SCOPE_AGENT) < (unsigned)(stage * 4))
            __builtin_amdgcn_s_sleep(8);
        asm volatile("" ::: "memory");
    }
    __syncthreads();
}

// LDS plan (137216 B static):
//  prep : cnt 44800 @0
//  embed: Bf[128][456] @0 (116736) | As[128][72] @116736 (18432) | Wex[4][128] @135168 (2048)
//  agg  : Bf @0 ; epilogue zl[128][136] @0 (34816, Bf dead) ; rs @116736 / rq @118784
//  post : zl @0 | coefs @34816 | hs[128][136] @35840 | Bw[128][72] @70656
//  tail : red @0 ; head pl/o0/o1 @0

// ---------------- prep: adjacency slab (block-private) + one-shot weight jobs ----------------

__device__ __forceinline__ void ph_prep(unsigned char* sm, int g, int q, int bid, int tid,
        const int* __restrict__ src, const int* __restrict__ dst, us* __restrict__ SbBF,
        const float* __restrict__ wa0, const float* __restrict__ wa1, const float* __restrict__ wa2,
        const float* __restrict__ wb0, const float* __restrict__ wb1, const float* __restrict__ wb2,
        us* __restrict__ wt0, us* __restrict__ wtb0, us* __restrict__ wta1,
        us* __restrict__ wtb1, us* __restrict__ wta2, us* __restrict__ wtb2,
        float* __restrict__ pstat, us* __restrict__ tT0, us* __restrict__ tT1, us* __restrict__ tT2) {
    int r0 = q * 112;
    int* cnt = (int*)sm;                      // 112*400 counts (u8 packed in ints)
    for (int i = tid; i < 11200; i += 1024) cnt[i] = 0;
    __syncthreads();
    int ebase = g * EPG, nbase = g * NPG;
    for (int e = tid; e < EPG; e += 1024) {
        int d = dst[ebase + e] - nbase;
        int dr = d - r0;
        if ((unsigned)dr < 112u) {
            int s = src[ebase + e] - nbase;
            int idx = dr * NPG + s;
            atomicAdd(&cnt[idx >> 2], (int)(1u << ((idx & 3) * 8)));
        }
    }
    __syncthreads();
    const unsigned char* cb = (const unsigned char*)cnt;
    for (int i = tid; i < 112 * 112; i += 1024) {
        int rr = i / 112, c4 = (i % 112) * 4;
        int R = r0 + rr;
        ushort4 o;
#pragma unroll
        for (int j = 0; j < 4; ++j) {
            int c = c4 + j;
            unsigned v = (R < NPG && c < NPG) ? (unsigned)cb[rr * NPG + c] + (c == R ? 1u : 0u) : 0u;
            ((unsigned short*)&o)[j] = (unsigned short)u8bf(v);
        }
        *(ushort4*)&SbBF[((size_t)g * 512 + R) * 448 + c4] = o;   // plain: block-private
    }
    if (q == 3) {   // zero pad rows 448..511 (read by over-spanned A fragments)
        for (int i = tid; i < 64 * 112; i += 1024) {
            int rr = 448 + i / 112, c4 = (i % 112) * 4;
            *(u64*)&SbBF[((size_t)g * 512 + rr) * 448 + c4] = 0ull;
        }
    }
    if (bid < 64) {    // distributed one-shot jobs; cross-block consumers -> ast64
        int idx = bid * 1024 + tid;          // 0..65535
        if (idx < 14336) {                   // wt0: [n=128][k=448] bf16, zero-padded K
            int n = idx / 112, k0 = (idx % 112) * 4;
            unsigned short o[4];
#pragma unroll
            for (int j = 0; j < 4; ++j) {
                int k = k0 + j;
                o[j] = (k < 400) ? f2bf(wa0[(size_t)k * 128 + n]) : (unsigned short)0;
            }
            ast64(&wt0[(size_t)n * 448 + k0], pk4(o[0], o[1], o[2], o[3]));
        } else if (idx < 34816) {            // 5 x [n=128][k=128] transposes
            int r2 = idx - 14336;
            int m = r2 >> 12, qi = r2 & 4095;
            int r = qi * 4, n = r >> 7, k = r & 127;
            const float* smat = (m == 0) ? wb0 : (m == 1) ? wa1 : (m == 2) ? wb1 : (m == 3) ? wa2 : wb2;
            us* dmat = (m == 0) ? wtb0 : (m == 1) ? wta1 : (m == 2) ? wtb1 : (m == 3) ? wta2 : wtb2;
            unsigned short o[4];
#pragma unroll
            for (int j = 0; j < 4; ++j) o[j] = f2bf(smat[(size_t)(k + j) * 128 + n]);
            ast64(&dmat[r], pk4(o[0], o[1], o[2], o[3]));
        } else if (idx < 45056) {            // zero pstat: 20480 f32 = 10240 u64
            int qi = idx - 34816;
            ast64(&((u64*)pstat)[qi], 0ull);
        } else if (idx < 45440) {            // zero tT tail slack (512 us x 3 buffers)
            int qi = idx - 45056;
            us* t = (qi < 128) ? tT0 : (qi < 256) ? tT1 : tT2;
            ast64(&t[(size_t)128 * N_NODES + (qi & 127) * 4], 0ull);
        }
    }
}

// ---------------- embed: tT0 = ([x | ge | he] @ W0a)^T for this block's 100-row quarter ----------------

__device__ __forceinline__ void ph_embed(unsigned char* sm, int g, int q, int tid,
        const float* __restrict__ x, const us* __restrict__ wt0, const float* __restrict__ wa0,
        const int* __restrict__ gid, const float* __restrict__ ge, const float* __restrict__ he,
        us* __restrict__ tTw) {
    us (*Bf)[456] = (us(*)[456])sm;
    us (*As)[72] = (us(*)[72])(sm + 116736);
    float (*Wex)[128] = (float(*)[128])(sm + 135168);
    int nb = g * NPG + q * 100;
    int wave = tid >> 6, lane = tid & 63;
    int wrow = wave >> 2, wc4 = wave & 3;
    int fm = lane & 15, quad = lane >> 4;

    // stage full W0^T panel (write-once by prep -> first-touch plain reads are fresh)
    for (int i = tid; i < 7168; i += 1024) {
        int col = i / 56, kq = (i % 56) * 8;
        *(short8*)&Bf[col][kq] = *(const short8*)(wt0 + (size_t)col * 448 + kq);
    }
    for (int i = tid; i < 512; i += 1024)
        Wex[i >> 7][i & 127] = wa0[(size_t)(400 + (i >> 7)) * 128 + (i & 127)];

    floatx4 acc[2][2];
#pragma unroll
    for (int rt = 0; rt < 2; ++rt)
#pragma unroll
        for (int ct = 0; ct < 2; ++ct) acc[rt][ct] = (floatx4){0.f, 0.f, 0.f, 0.f};

    const int rA = tid >> 3, kcA = (tid & 7) * 8;
    float v[8];
    auto loadK = [&](int ks) {
        int kg = ks * 64 + kcA;
        if (rA < 100) {
            const float* ar = x + (size_t)(nb + rA) * F_IN;
            if (kg + 7 < 400) {
                float4 a = *(const float4*)(ar + kg);
                float4 b = *(const float4*)(ar + kg + 4);
                v[0] = a.x; v[1] = a.y; v[2] = a.z; v[3] = a.w;
                v[4] = b.x; v[5] = b.y; v[6] = b.z; v[7] = b.w;
            } else {
#pragma unroll
                for (int j = 0; j < 8; ++j) v[j] = (kg + j < 400) ? ar[kg + j] : 0.f;
            }
        } else {
#pragma unroll
            for (int j = 0; j < 8; ++j) v[j] = 0.f;
        }
    };

    loadK(0);
    for (int ks = 0; ks < 7; ++ks) {
        {
            short8 s;
#pragma unroll
            for (int j = 0; j < 8; ++j) s[j] = (short)f2bf(v[j]);
            *(short8*)&As[rA][kcA] = s;
        }
        __syncthreads();            // first iter also covers Bf/Wex staging
        if (ks + 1 < 7) loadK(ks + 1);
#pragma unroll
        for (int k0l = 0; k0l < 64; k0l += 32) {
            short8 af[2], bf[2];
#pragma unroll
            for (int rt = 0; rt < 2; ++rt)
                af[rt] = *(const short8*)&As[wrow * 32 + rt * 16 + fm][k0l + quad * 8];
#pragma unroll
            for (int ct = 0; ct < 2; ++ct)
                bf[ct] = *(const short8*)&Bf[wc4 * 32 + ct * 16 + fm][ks * 64 + k0l + quad * 8];
#pragma unroll
            for (int rt = 0; rt < 2; ++rt)
#pragma unroll
                for (int ct = 0; ct < 2; ++ct)
                    acc[rt][ct] = __builtin_amdgcn_mfma_f32_16x16x32_bf16(
                        af[rt], bf[ct], acc[rt][ct], 0, 0, 0);
        }
        __syncthreads();
    }

#pragma unroll
    for (int rt = 0; rt < 2; ++rt)
#pragma unroll
        for (int ct = 0; ct < 2; ++ct) {
            int col = wc4 * 32 + ct * 16 + fm;
            int rl0 = wrow * 32 + rt * 16 + quad * 4;
            if (rl0 < 100) {
                unsigned short o[4];
#pragma unroll
                for (int r = 0; r < 4; ++r) {
                    int row = nb + rl0 + r;
                    int gv = gid[row];
                    float vv = acc[rt][ct][r]
                             + ge[gv * 2] * Wex[0][col] + ge[gv * 2 + 1] * Wex[1][col]
                             + he[(row & 1) * 2] * Wex[2][col] + he[(row & 1) * 2 + 1] * Wex[3][col];
                    o[r] = f2bf(vv);
                }
                ast64(&tTw[(size_t)col * N_NODES + nb + rl0], pk4(o[0], o[1], o[2], o[3]));
            }
        }
}

// ---------------- agg: z = (S+I)@t + ba ; z stays in LDS ; BN stat partials ----------------

__device__ __forceinline__ void ph_agg(unsigned char* sm, int g, int q, int tid,
        const us* __restrict__ SbBF, const us* __restrict__ tTr, const float* __restrict__ ba,
        float* __restrict__ psum, float* __restrict__ psq, int bucket) {
    us (*Bf)[456] = (us(*)[456])sm;
    us (*zl)[136] = (us(*)[136])sm;
    float (*rs)[4][2][16] = (float(*)[4][2][16])(sm + 116736);
    float (*rq)[4][2][16] = (float(*)[4][2][16])(sm + 118784);
    int wave = tid >> 6, lane = tid & 63;
    int wrow = wave >> 2, wc4 = wave & 3;
    int fm = lane & 15, quad = lane >> 4;
    int node0 = g * NPG;

    // stage tT panel with PLAIN 16B loads (buffer written once via ast64, read once -> fresh)
    for (int i = tid; i < 7168; i += 1024) {
        int col = i / 56, kq = (i % 56) * 8;
        *(short8*)&Bf[col][kq] = *(const short8*)(tTr + (size_t)col * N_NODES + node0 + kq);
    }
    __syncthreads();

    floatx4 acc[2][2];
#pragma unroll
    for (int rt = 0; rt < 2; ++rt)
#pragma unroll
        for (int ct = 0; ct < 2; ++ct) acc[rt][ct] = (floatx4){0.f, 0.f, 0.f, 0.f};

    const us* abase = SbBF + ((size_t)g * 512 + q * 112) * 448;
#pragma unroll
    for (int ks = 0; ks < 7; ++ks) {
#pragma unroll
        for (int k0l = 0; k0l < 64; k0l += 32) {
            short8 af[2], bf[2];
#pragma unroll
            for (int rt = 0; rt < 2; ++rt)
                af[rt] = *(const short8*)(abase + (size_t)(wrow * 32 + rt * 16 + fm) * 448
                                          + ks * 64 + k0l + quad * 8);
#pragma unroll
            for (int ct = 0; ct < 2; ++ct)
                bf[ct] = *(const short8*)&Bf[wc4 * 32 + ct * 16 + fm][ks * 64 + k0l + quad * 8];
#pragma unroll
            for (int rt = 0; rt < 2; ++rt)
#pragma unroll
                for (int ct = 0; ct < 2; ++ct)
                    acc[rt][ct] = __builtin_amdgcn_mfma_f32_16x16x32_bf16(
                        af[rt], bf[ct], acc[rt][ct], 0, 0, 0);
        }
    }
    __syncthreads();   // B panel dead; zl overlays it

    int nrows = (q < 3) ? 112 : 64;
    float sc[2] = {0.f, 0.f}, sq2[2] = {0.f, 0.f};
#pragma unroll
    for (int rt = 0; rt < 2; ++rt)
#pragma unroll
        for (int ct = 0; ct < 2; ++ct) {
            int col = wc4 * 32 + ct * 16 + fm;
            int rl0 = wrow * 32 + rt * 16 + quad * 4;
            if (rl0 < nrows) {
                float bv = ba[col];
#pragma unroll
                for (int r = 0; r < 4; ++r) {
                    float vv = acc[rt][ct][r] + bv;
                    zl[rl0 + r][col] = f2bf(vv);
                    sc[ct] += vv;
                    sq2[ct] += vv * vv;
                }
            }
        }
#pragma unroll
    for (int ct = 0; ct < 2; ++ct) {
        sc[ct] += __shfl_xor(sc[ct], 16);
        sc[ct] += __shfl_xor(sc[ct], 32);
        sq2[ct] += __shfl_xor(sq2[ct], 16);
        sq2[ct] += __shfl_xor(sq2[ct], 32);
    }
    if (lane < 16) {
#pragma unroll
        for (int ct = 0; ct < 2; ++ct) { rs[wrow][wc4][ct][lane] = sc[ct]; rq[wrow][wc4][ct][lane] = sq2[ct]; }
    }
    __syncthreads();
    if (tid < 128) {
        int wc = tid >> 5, ct = (tid >> 4) & 1, f = tid & 15;
        float S = 0.f, Q = 0.f;
#pragma unroll
        for (int wr = 0; wr < 4; ++wr) { S += rs[wr][wc][ct][f]; Q += rq[wr][wc][ct][f]; }
        atomicAdd(&psum[bucket * 128 + tid], S);
        atomicAdd(&psq[bucket * 128 + tid], Q);
    }
}

// ---------------- post: BN + h=relu(relu(affine(z))@wb+bb) [+ t'=h@wa_next | pool] ----------------

template <int FINAL>
__device__ __forceinline__ void ph_post(unsigned char* sm, int g, int q, int tid,
        const float* __restrict__ psum, const float* __restrict__ psq,
        const float* __restrict__ gamma, const float* __restrict__ beta,
        const us* __restrict__ wtb, const float* __restrict__ bb,
        const us* __restrict__ wta_next, us* __restrict__ tTw, float& p0, float& p1) {
    us (*zl)[136] = (us(*)[136])sm;
    float* coefs = (float*)(sm + 34816);
    us (*hs)[136] = (us(*)[136])(sm + 35840);
    us (*Bw)[72] = (us(*)[72])(sm + 70656);
    int wave = tid >> 6, lane = tid & 63;
    int wrow = wave >> 2, wc4 = wave & 3;
    int fm = lane & 15, quad = lane >> 4;
    int nrows = (q < 3) ? 112 : 64;
    int nb = g * NPG + q * 112;

    if (tid < 128) {
        float S = 0.f, Q = 0.f;
#pragma unroll
        for (int b = 0; b < 16; ++b) {
            S += __hip_atomic_load(&psum[b * 128 + tid], __ATOMIC_RELAXED, __HIP_MEMORY_SCOPE_AGENT);
            Q += __hip_atomic_load(&psq[b * 128 + tid], __ATOMIC_RELAXED, __HIP_MEMORY_SCOPE_AGENT);
        }
        float invn = 1.0f / (float)N_NODES;
        float mu = S * invn;
        float var = Q * invn - mu * mu;
        float a = gamma[tid] * rsqrtf(var + BN_EPS);
        coefs[tid] = a;
        coefs[128 + tid] = beta[tid] - a * mu;
    }
    __syncthreads();
    for (int i = tid; i < 16384; i += 1024) {
        int rl = i >> 7, col = i & 127;
        float vv = bf2f(zl[rl][col]);
        zl[rl][col] = f2bf(fmaxf(coefs[col] * vv + coefs[128 + col], 0.f));
    }
    __syncthreads();

    floatx4 acc[2][2];
#pragma unroll
    for (int rt = 0; rt < 2; ++rt)
#pragma unroll
        for (int ct = 0; ct < 2; ++ct) acc[rt][ct] = (floatx4){0.f, 0.f, 0.f, 0.f};

    const int nB = tid >> 3, kc = (tid & 7) * 8;
    for (int ks = 0; ks < 2; ++ks) {
        *(short8*)&Bw[nB][kc] = *(const short8*)(wtb + (size_t)nB * 128 + ks * 64 + kc);
        __syncthreads();
#pragma unroll
        for (int k0l = 0; k0l < 64; k0l += 32) {
            short8 af[2], bf[2];
#pragma unroll
            for (int rt = 0; rt < 2; ++rt)
                af[rt] = *(const short8*)&zl[wrow * 32 + rt * 16 + fm][ks * 64 + k0l + quad * 8];
#pragma unroll
            for (int ct = 0; ct < 2; ++ct)
                bf[ct] = *(const short8*)&Bw[wc4 * 32 + ct * 16 + fm][k0l + quad * 8];
#pragma unroll
            for (int rt = 0; rt < 2; ++rt)
#pragma unroll
                for (int ct = 0; ct < 2; ++ct)
                    acc[rt][ct] = __builtin_amdgcn_mfma_f32_16x16x32_bf16(
                        af[rt], bf[ct], acc[rt][ct], 0, 0, 0);
        }
        __syncthreads();
    }

    if (FINAL) {
#pragma unroll
        for (int rt = 0; rt < 2; ++rt)
#pragma unroll
            for (int ct = 0; ct < 2; ++ct) {
                int col = wc4 * 32 + ct * 16 + fm;
                int rl0 = wrow * 32 + rt * 16 + quad * 4;
                if (rl0 < nrows) {
                    float bv = bb[col];
                    float s = 0.f;
#pragma unroll
                    for (int r = 0; r < 4; ++r) s += fmaxf(acc[rt][ct][r] + bv, 0.f);
                    if (ct == 0) p0 += s; else p1 += s;
                }
            }
        return;
    }

#pragma unroll
    for (int rt = 0; rt < 2; ++rt)
#pragma unroll
        for (int ct = 0; ct < 2; ++ct) {
            int col = wc4 * 32 + ct * 16 + fm;
            float bv = bb[col];
            int rl0 = wrow * 32 + rt * 16 + quad * 4;
#pragma unroll
            for (int r = 0; r < 4; ++r)
                hs[rl0 + r][col] = f2bf(fmaxf(acc[rt][ct][r] + bv, 0.f));
        }
    __syncthreads();

#pragma unroll
    for (int rt = 0; rt < 2; ++rt)
#pragma unroll
        for (int ct = 0; ct < 2; ++ct) acc[rt][ct] = (floatx4){0.f, 0.f, 0.f, 0.f};

    for (int ks = 0; ks < 2; ++ks) {
        *(short8*)&Bw[nB][kc] = *(const short8*)(wta_next + (size_t)nB * 128 + ks * 64 + kc);
        __syncthreads();
#pragma unroll
        for (int k0l = 0; k0l < 64; k0l += 32) {
            short8 af[2], bf[2];
#pragma unroll
            for (int rt = 0; rt < 2; ++rt)
                af[rt] = *(const short8*)&hs[wrow * 32 + rt * 16 + fm][ks * 64 + k0l + quad * 8];
#pragma unroll
            for (int ct = 0; ct < 2; ++ct)
                bf[ct] = *(const short8*)&Bw[wc4 * 32 + ct * 16 + fm][k0l + quad * 8];
#pragma unroll
            for (int rt = 0; rt < 2; ++rt)
#pragma unroll
                for (int ct = 0; ct < 2; ++ct)
                    acc[rt][ct] = __builtin_amdgcn_mfma_f32_16x16x32_bf16(
                        af[rt], bf[ct], acc[rt][ct], 0, 0, 0);
        }
        __syncthreads();
    }

#pragma unroll
    for (int rt = 0; rt < 2; ++rt)
#pragma unroll
        for (int ct = 0; ct < 2; ++ct) {
            int col = wc4 * 32 + ct * 16 + fm;
            int rl0 = wrow * 32 + rt * 16 + quad * 4;
            if (rl0 < nrows) {
                unsigned short o[4];
#pragma unroll
                for (int r = 0; r < 4; ++r) o[r] = f2bf(acc[rt][ct][r]);
                ast64(&tTw[(size_t)col * N_NODES + nb + rl0], pk4(o[0], o[1], o[2], o[3]));
            }
        }
}

// ---------------- the single persistent kernel ----------------

__global__ __launch_bounds__(1024, 4) void persist_all(
        const float* __restrict__ x, const int* __restrict__ esrc, const int* __restrict__ edst,
        const int* __restrict__ gid, const float* __restrict__ ge, const float* __restrict__ he,
        const float* __restrict__ wa0, const float* __restrict__ ba0, const float* __restrict__ gg0,
        const float* __restrict__ be0, const float* __restrict__ wb0, const float* __restrict__ bbias0,
        const float* __restrict__ wa1, const float* __restrict__ ba1, const float* __restrict__ gg1,
        const float* __restrict__ be1, const float* __restrict__ wb1, const float* __restrict__ bbias1,
        const float* __restrict__ wa2, const float* __restrict__ ba2, const float* __restrict__ gg2,
        const float* __restrict__ be2, const float* __restrict__ wb2, const float* __restrict__ bbias2,
        const float* __restrict__ wfa, const float* __restrict__ bfa,
        const float* __restrict__ wfb, const float* __restrict__ bfb,
        us* __restrict__ tT0, us* __restrict__ tT1, us* __restrict__ tT2,
        us* __restrict__ SbBF, float* __restrict__ pstat,
        us* __restrict__ wt0, us* __restrict__ wtb0, us* __restrict__ wta1,
        us* __restrict__ wtb1, us* __restrict__ wta2, us* __restrict__ wtb2,
        unsigned* __restrict__ bar, float* __restrict__ out) {
    __shared__ __align__(16) unsigned char sm[137216];
    int bid = blockIdx.x, tid = threadIdx.x;
    // XCD swizzle: the 4 blocks of a graph are congruent mod 8 -> same XCD (perf hint only)
    int g = (bid & 7) * 8 + ((bid >> 3) & 7);
    int q = bid >> 6;
    unsigned* gc = bar + 544 + g * 32;
    float* pooled = pstat + 12288;
    float p0 = 0.f, p1 = 0.f;

    ph_prep(sm, g, q, bid, tid, esrc, edst, SbBF, wa0, wa1, wa2, wb0, wb1, wb2,
            wt0, wtb0, wta1, wtb1, wta2, wtb2, pstat, tT0, tT1, tT2);
    gsync_tree(bar, bid, 1);
    ph_embed(sm, g, q, tid, x, wt0, wa0, gid, ge, he, tT0);
    gbar4(gc, 1);

    ph_agg(sm, g, q, tid, SbBF, tT0, ba0, pstat + 0, pstat + 2048, bid & 15);
    gsync_tree(bar, bid, 2);
    ph_post<0>(sm, g, q, tid, pstat + 0, pstat + 2048, gg0, be0, wtb0, bbias0, wta1, tT1, p0, p1);
    gbar4(gc, 2);

    ph_agg(sm, g, q, tid, SbBF, tT1, ba1, pstat + 4096, pstat + 6144, bid & 15);
    gsync_tree(bar, bid, 3);
    ph_post<0>(sm, g, q, tid, pstat + 4096, pstat + 6144, gg1, be1, wtb1, bbias1, wta2, tT2, p0, p1);
    gbar4(gc, 3);

    ph_agg(sm, g, q, tid, SbBF, tT2, ba2, pstat + 8192, pstat + 10240, bid & 15);
    gsync_tree(bar, bid, 4);
    ph_post<1>(sm, g, q, tid, pstat + 8192, pstat + 10240, gg2, be2, wtb2, bbias2, nullptr, nullptr, p0, p1);

    {   // per-graph pool: block reduce then coherence-point atomics
        int wave = tid >> 6, lane = tid & 63;
        int wrow = wave >> 2, wc4 = wave & 3;
        float (*red)[4][2][16] = (float(*)[4][2][16])sm;
        p0 += __shfl_xor(p0, 16); p0 += __shfl_xor(p0, 32);
        p1 += __shfl_xor(p1, 16); p1 += __shfl_xor(p1, 32);
        __syncthreads();
        if (lane < 16) { red[wrow][wc4][0][lane] = p0; red[wrow][wc4][1][lane] = p1; }
        __syncthreads();
        if (tid < 128) {
            int wc = tid >> 5, ct = (tid >> 4) & 1, f = tid & 15;
            float s = 0.f;
#pragma unroll
            for (int wr = 0; wr < 4; ++wr) s += red[wr][wc][ct][f];
            atomicAdd(&pooled[g * 128 + tid], s);
        }
    }
    gbar4(gc, 4);

    if (q == 0) {   // head: one block per graph
        float* pl = (float*)sm;
        float* o0 = pl + 128;
        float* o1 = pl + 256;
        __syncthreads();
        if (tid < 128) {
            unsigned uv = __hip_atomic_load((const unsigned*)&pooled[g * 128 + tid],
                                            __ATOMIC_RELAXED, __HIP_MEMORY_SCOPE_AGENT);
            pl[tid] = __uint_as_float(uv);
        }
        __syncthreads();
        if (tid < 128) {
            float a = bfa[tid];
            for (int k = 0; k < 128; ++k) a += pl[k] * wfa[k * 128 + tid];
            float p2 = fmaxf(a, 0.f);
            o0[tid] = p2 * wfb[tid * 2 + 0];
            o1[tid] = p2 * wfb[tid * 2 + 1];
        }
        __syncthreads();
        if (tid == 0) {
            float a0 = bfb[0], a1 = bfb[1];
#pragma unroll
            for (int k = 0; k < 128; ++k) { a0 += o0[k]; a1 += o1[k]; }
            out[g * 2 + 0] = a0;
            out[g * 2 + 1] = a1;
        }
    }
}

// ---------------- launch ----------------

extern "C" void kernel_launch(void* const* d_in, const int* in_sizes, int n_in,
                              void* d_out, int out_size, void* d_ws, size_t ws_size,
                              hipStream_t stream) {
    const float* x   = (const float*)d_in[0];
    const int* ei    = (const int*)d_in[1];
    const int* gid   = (const int*)d_in[3];
    const float* ge  = (const float*)d_in[4];
    const float* he  = (const float*)d_in[5];
    float* out = (float*)d_out;

    char* ws = (char*)d_ws;
    size_t o = 0;
    auto alloc = [&](size_t bytes) { char* p = ws + o; o += (bytes + 255) & ~(size_t)255; return p; };
    size_t tbytes = ((size_t)128 * N_NODES + 512) * 2;
    us* tT0 = (us*)alloc(tbytes);
    us* tT1 = (us*)alloc(tbytes);
    us* tT2 = (us*)alloc(tbytes);
    us* SbBF = (us*)alloc((size_t)NB * 512 * 448 * 2);
    float* pstat = (float*)alloc(20480 * 4);
    us* wt0  = (us*)alloc(128 * 448 * 2);
    us* wtb0 = (us*)alloc(128 * 128 * 2);
    us* wta1 = (us*)alloc(128 * 128 * 2);
    us* wtb1 = (us*)alloc(128 * 128 * 2);
    us* wta2 = (us*)alloc(128 * 128 * 2);
    us* wtb2 = (us*)alloc(128 * 128 * 2);
    unsigned* bar = (unsigned*)alloc(12288);
    (void)ws_size; (void)in_sizes; (void)n_in; (void)out_size;

    hipMemsetAsync(bar, 0, 12288, stream);

    persist_all<<<NBLK, 1024, 0, stream>>>(
        x, ei, ei + NE, gid, ge, he,
        (const float*)d_in[6],  (const float*)d_in[7],  (const float*)d_in[8],
        (const float*)d_in[9],  (const float*)d_in[10], (const float*)d_in[11],
        (const float*)d_in[12], (const float*)d_in[13], (const float*)d_in[14],
        (const float*)d_in[15], (const float*)d_in[16], (const float*)d_in[17],
        (const float*)d_in[18], (const float*)d_in[19], (const float*)d_in[20],
        (const float*)d_in[21], (const float*)d_in[22], (const float*)d_in[23],
        (const float*)d_in[24], (const float*)d_in[25],
        (const float*)d_in[26], (const float*)d_in[27],
        tT0, tT1, tT2, SbBF, pstat, wt0, wtb0, wta1, wtb1, wta2, wtb2,
        bar, out);
}